// Round 6
// baseline (983.823 us; speedup 1.0000x reference)
//
#include <hip/hip_runtime.h>
#include <math.h>

#define TQ_  9

typedef unsigned int   u32;
typedef unsigned short ushort_t;
typedef short bf16x8 __attribute__((ext_vector_type(8)));
typedef float f32x4  __attribute__((ext_vector_type(4)));

__device__ __forceinline__ float bs2f(ushort_t s) {
  return __uint_as_float(((u32)s) << 16);
}
__device__ __forceinline__ ushort_t f2bs(float x) {   // round-to-nearest-even
  u32 u = __float_as_uint(x);
  u32 r = (u + 0x7FFFu + ((u >> 16) & 1u)) >> 16;
  return (ushort_t)r;
}

// ---------------------------------------------------------------------------
// Weight PACK: W f32 [K][N] -> MFMA-frag-linear bf16 (A-operand layout).
// Frag group G = (j*(K/32) + kk)*64 + q*16 + ln holds 8 bf16:
//   element e: out-col n = j*16+ln, k = kk*32 + q*8 + e.
// pm=1 (Q/K weights): out-columns permuted within each 32-col head so RoPE
// pairs (d, d+16) sit at positions c, c^8 of a 16-col chunk.
// ---------------------------------------------------------------------------
struct TPA { const float* s[10]; ushort_t* d[10]; int K[10]; int N[10]; int pm[10]; };

__global__ __launch_bounds__(256)
void pack_all_kernel(TPA p) {
  int z = blockIdx.z;
  int K = p.K[z], N = p.N[z];
  int bn = blockIdx.x << 5, bk = blockIdx.y << 5;
  if (bn >= N || bk >= K) return;
  const float* W = p.s[z];
  ushort_t* pk = p.d[z];
  int pm = p.pm[z];
  __shared__ float t[32][33];                 // [k_local][n_local]
  int tid = threadIdx.x;
  int tx = tid & 31, ty = tid >> 5;
  #pragma unroll
  for (int r = 0; r < 4; ++r)
    t[ty + (r << 3)][tx] = W[(long)(bk + ty + (r << 3)) * N + bn + tx];
  __syncthreads();
  if (tid < 128) {
    int jl = tid >> 6, q = (tid >> 4) & 3, ln = tid & 15;
    int j = (bn >> 4) + jl, kk = bk >> 5;
    int colsrc = pm ? ((ln & 7) + (jl << 3) + ((ln & 8) << 1))
                    : ((jl << 4) + ln);
    long G = (((long)j * (K >> 5) + kk) << 6) + (q << 4) + ln;
    bf16x8 ov;
    #pragma unroll
    for (int e = 0; e < 8; ++e)
      ov[e] = (short)f2bs(t[(q << 3) + e][colsrc]);
    *(bf16x8*)(pk + (G << 3)) = ov;
  }
}

// concat 3 biases x 2 stages into f32 [2][768]; Q/K parts permuted to match
struct BC6 { const float* b[6]; };
__global__ __launch_bounds__(768)
void bias_concat_kernel(BC6 p, float* __restrict__ dst) {
  int z = blockIdx.x, n = threadIdx.x;
  int w = n >> 8, q = n & 255;
  int psrc = q;
  if (w < 2)
    psrc = (q & 0xE0) | (q & 7) | (((q >> 4) & 1) << 3) | (((q >> 3) & 1) << 4);
  dst[z * 768 + n] = p.b[z * 3 + w][psrc];
}

// ---------------------------------------------------------------------------
// LayerNorm materialize: one wave per row (4 rows/block), float4 loads.
// ---------------------------------------------------------------------------
__global__ __launch_bounds__(256)
void ln_norm_kernel(const float* __restrict__ src, int spatial,
                    const float* __restrict__ g, const float* __restrict__ b,
                    ushort_t* __restrict__ dst) {
  int row = blockIdx.x * 4 + (threadIdx.x >> 6);
  int lane = threadIdx.x & 63;
  long srow = row;
  if (spatial) {
    int bq = row >> 13, r = row & 8191;
    srow = ((long)(bq * TQ_ + (r >> 10)) << 10) + (r & 1023);
  }
  float4 v = ((const float4*)(src + srow * 256))[lane];
  float s  = v.x + v.y + v.z + v.w;
  float s2 = v.x * v.x + v.y * v.y + v.z * v.z + v.w * v.w;
  #pragma unroll
  for (int m = 32; m; m >>= 1) {
    s  += __shfl_xor(s,  m, 64);
    s2 += __shfl_xor(s2, m, 64);
  }
  float mean = s * (1.f / 256.f);
  float rstd = rsqrtf(s2 * (1.f / 256.f) - mean * mean + 1e-5f);
  float4 gv = ((const float4*)g)[lane];
  float4 bv = ((const float4*)b)[lane];
  ushort_t o[4];
  o[0] = f2bs((v.x - mean) * rstd * gv.x + bv.x);
  o[1] = f2bs((v.y - mean) * rstd * gv.y + bv.y);
  o[2] = f2bs((v.z - mean) * rstd * gv.z + bv.z);
  o[3] = f2bs((v.w - mean) * rstd * gv.w + bv.w);
  u32 lo = (u32)o[0] | ((u32)o[1] << 16);
  u32 hi = (u32)o[2] | ((u32)o[3] << 16);
  uint2 pk; pk.x = lo; pk.y = hi;
  *(uint2*)(dst + (long)row * 256 + lane * 4) = pk;
}

// ---------------------------------------------------------------------------
// Barrier-free register-streaming GEMM (no LDS), swapped operand order:
//   D = W_frag (A-op, n-rows) x X_frag (B-op, m-cols) -> lane-contiguous cols.
// (unchanged from round 5 — passed, 4 attn-stage GEMMs only now)
// ---------------------------------------------------------------------------
template<int K>
__global__ __launch_bounds__(256, 4)
void wgemm_kernel(const ushort_t* __restrict__ A, int lda,
                  const ushort_t* __restrict__ packW,
                  const float* __restrict__ bias, const float* __restrict__ resid,
                  float* __restrict__ Cf, ushort_t* __restrict__ Cb,
                  int N, int NBq, int resid_mode, int out_mode, int act, int rope) {
  constexpr int K32 = K / 32;
  constexpr int AD = (K32 >= 4) ? 4 : K32;    // X prefetch depth (reg ring)
  constexpr int BD = 2;                       // W prefetch depth

  int tid = threadIdx.x;
  int wv = tid >> 6, lane = tid & 63;
  int ln = lane & 15, q4 = lane >> 4;

  // XCD-grouping decode
  int gid = blockIdx.x;
  int g = gid >> 5, r = gid & 31;
  int nq = (r >> 3) + ((g % NBq) << 2);
  int mb = ((g / NBq) << 3) + (r & 7);
  int m0 = mb << 7, n0 = nq << 6;

  const ushort_t* Ap = A + (long)(m0 + (wv << 5) + ln) * lda + (q4 << 3);
  long a16 = (long)lda << 4;                  // +16 rows
  const ushort_t* Bp = packW + (((long)(nq << 2) * K32) << 9) + (lane << 3);

  bf16x8 xr[AD][2];                           // X fragments (B-operand)
  bf16x8 wr[BD][4];                           // W fragments (A-operand)
  #pragma unroll
  for (int d = 0; d < BD; ++d)
    #pragma unroll
    for (int j = 0; j < 4; ++j)
      wr[d][j] = *(const bf16x8*)(Bp + (((long)j * K32 + d) << 9));
  #pragma unroll
  for (int d = 0; d < AD; ++d) {
    xr[d][0] = *(const bf16x8*)(Ap + d * 32);
    xr[d][1] = *(const bf16x8*)(Ap + a16 + d * 32);
  }

  f32x4 acc[2][4];
  #pragma unroll
  for (int i = 0; i < 2; ++i)
    #pragma unroll
    for (int j = 0; j < 4; ++j) acc[i][j] = 0.f;

  #pragma unroll
  for (int kk = 0; kk < K32; ++kk) {          // fully unrolled: static indices
    #pragma unroll
    for (int i = 0; i < 2; ++i)
      #pragma unroll
      for (int j = 0; j < 4; ++j)
        acc[i][j] = __builtin_amdgcn_mfma_f32_16x16x32_bf16(
            wr[kk % BD][j], xr[kk % AD][i], acc[i][j], 0, 0, 0);
    if (kk + AD < K32) {
      xr[kk % AD][0] = *(const bf16x8*)(Ap + (kk + AD) * 32);
      xr[kk % AD][1] = *(const bf16x8*)(Ap + a16 + (kk + AD) * 32);
    }
    if (kk + BD < K32) {
      #pragma unroll
      for (int j = 0; j < 4; ++j)
        wr[kk % BD][j] = *(const bf16x8*)(Bp + (((long)j * K32 + kk + BD) << 9));
    }
    __builtin_amdgcn_sched_barrier(0);        // pin prefetch distance
  }

  // ---- epilogue (all lane-contiguous: float4 / uint2) ----
  float4 bj[4];
  #pragma unroll
  for (int j = 0; j < 4; ++j)
    bj[j] = *(const float4*)(bias + n0 + (j << 4) + (q4 << 2));

  float cs_c[2][4], cs_s[2][4];
  if (rope) {
    int t = (m0 >> 10) % TQ_;
    #pragma unroll
    for (int p = 0; p < 2; ++p)
      #pragma unroll
      for (int r2 = 0; r2 < 4; ++r2) {
        float d = (float)(((q4 & 1) << 2) + r2 + (p << 3));
        float ang = (float)t * exp2f(d * -0.8304820237218406f);
        cs_c[p][r2] = cosf(ang);
        float s = sinf(ang);
        cs_s[p][r2] = (q4 & 2) ? s : -s;      // x1 lanes: -s, x2 lanes: +s
      }
  }

  #pragma unroll
  for (int i = 0; i < 2; ++i) {
    int m = m0 + (wv << 5) + (i << 4) + ln;   // per-lane output row
    long orow = m;
    if (out_mode == 1 || resid_mode == 2) {
      int bq = m >> 13, rr = m & 8191;
      orow = ((long)(bq * TQ_ + (rr >> 10)) << 10) + (rr & 1023);
    }
    #pragma unroll
    for (int j = 0; j < 4; ++j) {
      int n = n0 + (j << 4) + (q4 << 2);      // 4 consecutive cols per lane
      float v[4];
      #pragma unroll
      for (int r2 = 0; r2 < 4; ++r2) v[r2] = acc[i][j][r2] + bj[j][r2];
      if (rope && ((nq << 2) + j) < 32) {     // Q,K region (first 512 cols)
        #pragma unroll
        for (int r2 = 0; r2 < 4; ++r2) {
          float other = __shfl_xor(v[r2], 32, 64);
          v[r2] = v[r2] * cs_c[j & 1][r2] + other * cs_s[j & 1][r2];
        }
      }
      if (act) {
        #pragma unroll
        for (int r2 = 0; r2 < 4; ++r2) {
          float x = v[r2];
          v[r2] = 0.5f * x * (1.f + erff(x * 0.70710678118654752f));
        }
      }
      if (resid_mode == 1) {
        float4 rv = *(const float4*)(resid + (long)m * 256 + n);
        v[0] += rv.x; v[1] += rv.y; v[2] += rv.z; v[3] += rv.w;
      } else if (resid_mode == 2) {
        float4 rv = *(const float4*)(resid + orow * 256 + n);
        v[0] += rv.x; v[1] += rv.y; v[2] += rv.z; v[3] += rv.w;
      }
      if (out_mode == 2) {
        uint2 pk;
        pk.x = (u32)f2bs(v[0]) | ((u32)f2bs(v[1]) << 16);
        pk.y = (u32)f2bs(v[2]) | ((u32)f2bs(v[3]) << 16);
        *(uint2*)(Cb + (long)m * N + n) = pk;
      } else {
        float4 o4; o4.x = v[0]; o4.y = v[1]; o4.z = v[2]; o4.w = v[3];
        if (out_mode == 1) *(float4*)(Cf + orow * 256 + n) = o4;
        else               *(float4*)(Cf + (long)m * N + n) = o4;
      }
    }
  }
}

// ---------------------------------------------------------------------------
// FUSED MLP: out = x + (gelu(LN(x) @ W1 + b1) @ W2 + b2), in place on x.
// One WAVE per 32 rows (64-thread block, 1152 blocks). Zero barriers; all
// LDS traffic is same-wave (DS pipe is in-order). Eliminates the 151 MB
// hid round-trip + ln_norm dispatch + 2 GEMM dispatches.
//   1) LN: row stats via lane-partial sums + shfl_xor(16/32) across q4
//      groups; normalized bf16 X tile (32x256) -> XL (rotation-swizzled).
//   2) 16 chunks of 64 hid cols: w1 (64 MFMA, W1 frags from L2-resident
//      frag-linear pack) -> +b1 -> gelu -> pack bf16 -> HL (4 KB swizzled
//      lane-transpose scratch) -> read as w2 B-frags -> w2 (64 MFMA into
//      f32x4 acc[2][16], 128 VGPR).
//   3) epilogue: +b2 +x (resid), float4 stores.
// Swizzle: 16B-group rotation g' = (g + row) & (G-1): read/write bank spread
// <=4-way (free-ish); same mapping both sides (rule #21).
// ---------------------------------------------------------------------------
__device__ __forceinline__ int xl_off(int row, int col) {   // elems; XL 32x256
  return (row << 8) + (((((col >> 3) + row) & 31)) << 3) + (col & 7);
}
__device__ __forceinline__ int hl_off(int row, int col) {   // elems; HL 32x64
  return (row << 6) + (((((col >> 3) + row) & 7)) << 3) + (col & 7);
}

__global__ __launch_bounds__(64)
void mlp_fused_kernel(float* xio,                       // in/out (same buffer)
                      const ushort_t* __restrict__ W1p, // packed [1024][256]
                      const float* __restrict__ b1,
                      const ushort_t* __restrict__ W2p, // packed [256][1024]
                      const float* __restrict__ b2,
                      const float* __restrict__ g,
                      const float* __restrict__ be) {
  __shared__ ushort_t XL[8192];   // 16 KB normalized X tile
  __shared__ ushort_t HL[2048];   // 4 KB hid transpose scratch
  int lane = threadIdx.x;
  int ln = lane & 15, q4 = lane >> 4;
  int m0 = blockIdx.x << 5;

  // ---- LN pass 1: row sums (rows ln, ln+16; cols q4*8+32ks) ----
  float mean[2], rstd[2];
  #pragma unroll
  for (int i = 0; i < 2; ++i) {
    const float* xr = xio + (long)(m0 + (i << 4) + ln) * 256 + (q4 << 3);
    float s = 0.f, s2 = 0.f;
    #pragma unroll
    for (int ks = 0; ks < 8; ++ks) {
      float4 a = *(const float4*)(xr + (ks << 5));
      float4 b = *(const float4*)(xr + (ks << 5) + 4);
      s  += a.x + a.y + a.z + a.w + b.x + b.y + b.z + b.w;
      s2 += a.x*a.x + a.y*a.y + a.z*a.z + a.w*a.w
          + b.x*b.x + b.y*b.y + b.z*b.z + b.w*b.w;
    }
    s  += __shfl_xor(s,  16, 64);  s  += __shfl_xor(s,  32, 64);
    s2 += __shfl_xor(s2, 16, 64);  s2 += __shfl_xor(s2, 32, 64);
    mean[i] = s * (1.f / 256.f);
    rstd[i] = rsqrtf(s2 * (1.f / 256.f) - mean[i] * mean[i] + 1e-5f);
  }

  // ---- LN pass 2: normalize -> bf16 -> XL ----
  #pragma unroll
  for (int ks = 0; ks < 8; ++ks) {
    int col = (q4 << 3) + (ks << 5);
    float4 ga = *(const float4*)(g + col);
    float4 gb = *(const float4*)(g + col + 4);
    float4 ba = *(const float4*)(be + col);
    float4 bb = *(const float4*)(be + col + 4);
    #pragma unroll
    for (int i = 0; i < 2; ++i) {
      const float* xr = xio + (long)(m0 + (i << 4) + ln) * 256 + col;
      float4 a = *(const float4*)(xr);
      float4 b = *(const float4*)(xr + 4);
      float m_ = mean[i], r_ = rstd[i];
      u32 w0 = (u32)f2bs((a.x - m_) * r_ * ga.x + ba.x)
             | ((u32)f2bs((a.y - m_) * r_ * ga.y + ba.y) << 16);
      u32 w1_ = (u32)f2bs((a.z - m_) * r_ * ga.z + ba.z)
             | ((u32)f2bs((a.w - m_) * r_ * ga.w + ba.w) << 16);
      u32 w2_ = (u32)f2bs((b.x - m_) * r_ * gb.x + bb.x)
             | ((u32)f2bs((b.y - m_) * r_ * gb.y + bb.y) << 16);
      u32 w3 = (u32)f2bs((b.z - m_) * r_ * gb.z + bb.z)
             | ((u32)f2bs((b.w - m_) * r_ * gb.w + bb.w) << 16);
      uint4 pk; pk.x = w0; pk.y = w1_; pk.z = w2_; pk.w = w3;
      *(uint4*)&XL[xl_off((i << 4) + ln, col)] = pk;
    }
  }

  f32x4 acc[2][16];
  #pragma unroll
  for (int i = 0; i < 2; ++i)
    #pragma unroll
    for (int jo = 0; jo < 16; ++jo) acc[i][jo] = 0.f;

  // ---- 16 chunks of 64 hid cols ----
  #pragma unroll 1
  for (int c = 0; c < 16; ++c) {
    f32x4 h[2][4];
    #pragma unroll
    for (int i = 0; i < 2; ++i)
      #pragma unroll
      for (int jj = 0; jj < 4; ++jj) h[i][jj] = 0.f;

    #pragma unroll
    for (int ks = 0; ks < 8; ++ks) {
      int col = (q4 << 3) + (ks << 5);
      bf16x8 xf0 = *(const bf16x8*)&XL[xl_off(ln, col)];
      bf16x8 xf1 = *(const bf16x8*)&XL[xl_off(16 + ln, col)];
      #pragma unroll
      for (int jj = 0; jj < 4; ++jj) {
        bf16x8 wf = *(const bf16x8*)(W1p +
            (((long)((c << 2) + jj) * 8 + ks) << 9) + (lane << 3));
        h[0][jj] = __builtin_amdgcn_mfma_f32_16x16x32_bf16(wf, xf0, h[0][jj], 0, 0, 0);
        h[1][jj] = __builtin_amdgcn_mfma_f32_16x16x32_bf16(wf, xf1, h[1][jj], 0, 0, 0);
      }
    }
    // +b1, gelu, pack -> HL (lane-transpose scratch, same-wave)
    #pragma unroll
    for (int jj = 0; jj < 4; ++jj) {
      float4 b1v = *(const float4*)(b1 + (c << 6) + (jj << 4) + (q4 << 2));
      #pragma unroll
      for (int i = 0; i < 2; ++i) {
        float v[4];
        v[0] = h[i][jj][0] + b1v.x;  v[1] = h[i][jj][1] + b1v.y;
        v[2] = h[i][jj][2] + b1v.z;  v[3] = h[i][jj][3] + b1v.w;
        #pragma unroll
        for (int r = 0; r < 4; ++r)
          v[r] = 0.5f * v[r] * (1.f + erff(v[r] * 0.70710678118654752f));
        uint2 pk;
        pk.x = (u32)f2bs(v[0]) | ((u32)f2bs(v[1]) << 16);
        pk.y = (u32)f2bs(v[2]) | ((u32)f2bs(v[3]) << 16);
        *(uint2*)&HL[hl_off((i << 4) + ln, (jj << 4) + (q4 << 2))] = pk;
      }
    }
    // read back as w2 B-frags; w2 MFMA into out acc
    #pragma unroll
    for (int ks2 = 0; ks2 < 2; ++ks2) {
      bf16x8 hb0 = *(const bf16x8*)&HL[hl_off(ln,      (ks2 << 5) + (q4 << 3))];
      bf16x8 hb1 = *(const bf16x8*)&HL[hl_off(16 + ln, (ks2 << 5) + (q4 << 3))];
      #pragma unroll
      for (int jo = 0; jo < 16; ++jo) {
        bf16x8 wf = *(const bf16x8*)(W2p +
            (((long)(jo << 5) + (c << 1) + ks2) << 9) + (lane << 3));
        acc[0][jo] = __builtin_amdgcn_mfma_f32_16x16x32_bf16(wf, hb0, acc[0][jo], 0, 0, 0);
        acc[1][jo] = __builtin_amdgcn_mfma_f32_16x16x32_bf16(wf, hb1, acc[1][jo], 0, 0, 0);
      }
    }
  }

  // ---- epilogue: +b2 +resid(x), float4 stores, in place ----
  #pragma unroll
  for (int i = 0; i < 2; ++i) {
    long ro = (long)(m0 + (i << 4) + ln) * 256;
    #pragma unroll
    for (int jo = 0; jo < 16; ++jo) {
      int colb = (jo << 4) + (q4 << 2);
      float4 rv = *(const float4*)(xio + ro + colb);
      float4 bv = *(const float4*)(b2 + colb);
      float4 o;
      o.x = acc[i][jo][0] + bv.x + rv.x;
      o.y = acc[i][jo][1] + bv.y + rv.y;
      o.z = acc[i][jo][2] + bv.z + rv.z;
      o.w = acc[i][jo][3] + bv.w + rv.w;
      *(float4*)(xio + ro + colb) = o;
    }
  }
}

// ---------------------------------------------------------------------------
// Spatial 3x3 windowed attention on packed QKV [m][768] bf16.
// ---------------------------------------------------------------------------
__global__ __launch_bounds__(256)
void spatial_attn_kernel(ushort_t* __restrict__ qkv) {
  int gid = blockIdx.x * 256 + threadIdx.x;   // 262144
  int head = gid & 7, pixel = gid >> 3;
  int pix = pixel & 1023, bt = pixel >> 10;
  int y = pix >> 5, x = pix & 31;
  long rb = (long)bt << 10;
  const float scale = 0.17677669529663687f;   // 1/sqrt(32)

  float qf[32];
  long qoff = (long)pixel * 768 + head * 32;
  #pragma unroll
  for (int i = 0; i < 4; ++i) {
    bf16x8 t = *(const bf16x8*)(qkv + qoff + i * 8);
    #pragma unroll
    for (int e = 0; e < 8; ++e) qf[i * 8 + e] = bs2f((ushort_t)t[e]);
  }

  float s[9];
  bool val[9];
  #pragma unroll
  for (int n = 0; n < 9; ++n) {
    int yy = y + n / 3 - 1, xx = x + n % 3 - 1;
    bool ok = ((unsigned)yy < 32u) & ((unsigned)xx < 32u);
    val[n] = ok;
    float d = 0.f;
    if (ok) {
      long ko = (rb + (yy << 5) + xx) * 768 + 256 + head * 32;
      #pragma unroll
      for (int i = 0; i < 4; ++i) {
        bf16x8 t = *(const bf16x8*)(qkv + ko + i * 8);
        #pragma unroll
        for (int e = 0; e < 8; ++e) d += qf[i * 8 + e] * bs2f((ushort_t)t[e]);
      }
    }
    s[n] = d * scale;
  }
  float mx = -1e30f;
  #pragma unroll
  for (int n = 0; n < 9; ++n) if (val[n]) mx = fmaxf(mx, s[n]);
  float sum = 0.f;
  #pragma unroll
  for (int n = 0; n < 9; ++n) { s[n] = val[n] ? __expf(s[n] - mx) : 0.f; sum += s[n]; }
  float inv = 1.f / sum;

  float o[32];
  #pragma unroll
  for (int i = 0; i < 32; ++i) o[i] = 0.f;
  #pragma unroll
  for (int n = 0; n < 9; ++n) {
    if (val[n]) {
      int yy = y + n / 3 - 1, xx = x + n % 3 - 1;
      long vo = (rb + (yy << 5) + xx) * 768 + 512 + head * 32;
      #pragma unroll
      for (int i = 0; i < 4; ++i) {
        bf16x8 t = *(const bf16x8*)(qkv + vo + i * 8);
        #pragma unroll
        for (int e = 0; e < 8; ++e) o[i * 8 + e] += s[n] * bs2f((ushort_t)t[e]);
      }
    }
  }
  #pragma unroll
  for (int i = 0; i < 4; ++i) {
    bf16x8 t;
    #pragma unroll
    for (int e = 0; e < 8; ++e) t[e] = (short)f2bs(o[i * 8 + e] * inv);
    *(bf16x8*)(qkv + qoff + i * 8) = t;
  }
}

// ---------------------------------------------------------------------------
// Temporal attention (full 9x9; mask all-False). o over q in-place.
// ---------------------------------------------------------------------------
__global__ __launch_bounds__(256)
void temporal_attn_kernel(ushort_t* __restrict__ qkv) {
  int tid = threadIdx.x;
  int head = tid & 7, hwi = tid >> 3;
  int bi = blockIdx.x;                          // 1152 = 9 * 4 * 32
  int tq = bi >> 7;
  int rest = bi & 127;
  int b = rest >> 5, hwg = rest & 31;
  int hw = (hwg << 5) + hwi;
  long base = (long)(b * TQ_) * 1024 + hw;
  const float scale = 0.17677669529663687f;

  float qf[32];
  long qoff = (base + (long)tq * 1024) * 768 + head * 32;
  #pragma unroll
  for (int i = 0; i < 4; ++i) {
    bf16x8 t = *(const bf16x8*)(qkv + qoff + i * 8);
    #pragma unroll
    for (int e = 0; e < 8; ++e) qf[i * 8 + e] = bs2f((ushort_t)t[e]);
  }
  float s[9];
  #pragma unroll
  for (int tk = 0; tk < 9; ++tk) {
    long ko = (base + (long)tk * 1024) * 768 + 256 + head * 32;
    float d = 0.f;
    #pragma unroll
    for (int i = 0; i < 4; ++i) {
      bf16x8 t = *(const bf16x8*)(qkv + ko + i * 8);
      #pragma unroll
      for (int e = 0; e < 8; ++e) d += qf[i * 8 + e] * bs2f((ushort_t)t[e]);
    }
    s[tk] = d * scale;
  }
  float mx = s[0];
  #pragma unroll
  for (int tk = 1; tk < 9; ++tk) mx = fmaxf(mx, s[tk]);
  float sum = 0.f;
  #pragma unroll
  for (int tk = 0; tk < 9; ++tk) { s[tk] = __expf(s[tk] - mx); sum += s[tk]; }
  float inv = 1.f / sum;

  float o[32];
  #pragma unroll
  for (int i = 0; i < 32; ++i) o[i] = 0.f;
  #pragma unroll
  for (int tk = 0; tk < 9; ++tk) {
    long vo = (base + (long)tk * 1024) * 768 + 512 + head * 32;
    #pragma unroll
    for (int i = 0; i < 4; ++i) {
      bf16x8 t = *(const bf16x8*)(qkv + vo + i * 8);
      #pragma unroll
      for (int e = 0; e < 8; ++e) o[i * 8 + e] += s[tk] * bs2f((ushort_t)t[e]);
    }
  }
  #pragma unroll
  for (int i = 0; i < 4; ++i) {
    bf16x8 t;
    #pragma unroll
    for (int e = 0; e < 8; ++e) t[e] = (short)f2bs(o[i * 8 + e] * inv);
    *(bf16x8*)(qkv + qoff + i * 8) = t;
  }
}

// copy query frame 8 into x (f32); identical linear indices in both buffers
__global__ __launch_bounds__(256)
void copy_frame8_kernel(const float* __restrict__ qy, float* __restrict__ x) {
  long i = (long)blockIdx.x * 256 + threadIdx.x;
  int b = (int)(i >> 18);
  long rem = i & ((1L << 18) - 1);
  long gi = ((long)(b * TQ_ + 8) << 18) + rem;
  x[gi] = qy[gi];
}

// CLS frame mean over spatial: partial sums then broadcast (on f32 x)
__global__ __launch_bounds__(256)
void cls_sum_kernel(const float* __restrict__ x, float* __restrict__ partial) {
  int b = blockIdx.x >> 5, ch = blockIdx.x & 31;
  int d = threadIdx.x;
  long base = ((long)(b * TQ_) * 1024 + ch * 32) * 256 + d;
  float s = 0.f;
  for (int r = 0; r < 32; ++r) s += x[base + (long)r * 256];
  partial[(long)blockIdx.x * 256 + d] = s;
}

__global__ __launch_bounds__(256)
void cls_bcast_kernel(float* __restrict__ x, const float* __restrict__ partial) {
  int b = blockIdx.x >> 3, seg = blockIdx.x & 7;
  int d = threadIdx.x;
  float s = 0.f;
  for (int j = 0; j < 32; ++j) s += partial[(long)(b * 32 + j) * 256 + d];
  s *= (1.f / 1024.f);
  long base = ((long)(b * TQ_) * 1024 + seg * 128) * 256 + d;
  for (int r = 0; r < 128; ++r) x[base + (long)r * 256] = s;
}

// ---------------------------------------------------------------------------
extern "C" void kernel_launch(void* const* d_in, const int* in_sizes, int n_in,
                              void* d_out, int out_size, void* d_ws, size_t ws_size,
                              hipStream_t stream) {
  (void)in_sizes; (void)n_in; (void)out_size; (void)ws_size;
  const float* query = (const float*)d_in[0];
  const float* sln_g = (const float*)d_in[3];
  const float* sln_b = (const float*)d_in[4];
  const float* s_wq  = (const float*)d_in[5];
  const float* s_bq  = (const float*)d_in[6];
  const float* s_wk  = (const float*)d_in[7];
  const float* s_bk  = (const float*)d_in[8];
  const float* s_wv  = (const float*)d_in[9];
  const float* s_bv  = (const float*)d_in[10];
  const float* s_wo  = (const float*)d_in[11];
  const float* s_bo  = (const float*)d_in[12];
  const float* tln_g = (const float*)d_in[13];
  const float* tln_b = (const float*)d_in[14];
  const float* t_wq  = (const float*)d_in[15];
  const float* t_bq  = (const float*)d_in[16];
  const float* t_wk  = (const float*)d_in[17];
  const float* t_bk  = (const float*)d_in[18];
  const float* t_wv  = (const float*)d_in[19];
  const float* t_bv  = (const float*)d_in[20];
  const float* t_wo  = (const float*)d_in[21];
  const float* t_bo  = (const float*)d_in[22];
  const float* mln_g = (const float*)d_in[23];
  const float* mln_b = (const float*)d_in[24];
  const float* w1    = (const float*)d_in[25];
  const float* b1    = (const float*)d_in[26];
  const float* w2    = (const float*)d_in[27];
  const float* b2    = (const float*)d_in[28];
  float* out = (float*)d_out;

  // ---- workspace ----
  const long RB = 36864L * 256;
  ushort_t* XA  = (ushort_t*)d_ws;          // RB bf16
  ushort_t* QKV = XA + RB;                  // 3*RB bf16, rows of 768
  float*    P4  = (float*)(QKV + 3 * RB);   // RB f32
  ushort_t* wt  = (ushort_t*)(P4 + RB);     // 2 MB packed weights
  float* bias2  = (float*)(wt + 1048576);   // 2x768 f32
  float* clsp   = bias2 + 1536;             // 128*256 f32

  ushort_t* pk_sqkv = wt;                   // packed [768][256]
  ushort_t* pk_tqkv = wt + 196608;          // packed [768][256]
  ushort_t* pk_swo  = wt + 393216;          // packed [256][256]
  ushort_t* pk_two  = wt + 458752;          // packed [256][256]
  ushort_t* pk_w1   = wt + 524288;          // packed [1024][256]
  ushort_t* pk_w2   = wt + 786432;          // packed [256][1024]

  // ---- weight / bias prep (one pack dispatch) ----
  TPA tp;
  tp.s[0] = s_wq; tp.d[0] = pk_sqkv;          tp.K[0] = 256;  tp.N[0] = 256;  tp.pm[0] = 1;
  tp.s[1] = s_wk; tp.d[1] = pk_sqkv + 65536;  tp.K[1] = 256;  tp.N[1] = 256;  tp.pm[1] = 1;
  tp.s[2] = s_wv; tp.d[2] = pk_sqkv + 131072; tp.K[2] = 256;  tp.N[2] = 256;  tp.pm[2] = 0;
  tp.s[3] = t_wq; tp.d[3] = pk_tqkv;          tp.K[3] = 256;  tp.N[3] = 256;  tp.pm[3] = 1;
  tp.s[4] = t_wk; tp.d[4] = pk_tqkv + 65536;  tp.K[4] = 256;  tp.N[4] = 256;  tp.pm[4] = 1;
  tp.s[5] = t_wv; tp.d[5] = pk_tqkv + 131072; tp.K[5] = 256;  tp.N[5] = 256;  tp.pm[5] = 0;
  tp.s[6] = s_wo; tp.d[6] = pk_swo;           tp.K[6] = 256;  tp.N[6] = 256;  tp.pm[6] = 0;
  tp.s[7] = t_wo; tp.d[7] = pk_two;           tp.K[7] = 256;  tp.N[7] = 256;  tp.pm[7] = 0;
  tp.s[8] = w1;   tp.d[8] = pk_w1;            tp.K[8] = 256;  tp.N[8] = 1024; tp.pm[8] = 0;
  tp.s[9] = w2;   tp.d[9] = pk_w2;            tp.K[9] = 1024; tp.N[9] = 256;  tp.pm[9] = 0;
  pack_all_kernel<<<dim3(32, 32, 10), 256, 0, stream>>>(tp);
  BC6 bc;
  bc.b[0] = s_bq; bc.b[1] = s_bk; bc.b[2] = s_bv;
  bc.b[3] = t_bq; bc.b[4] = t_bk; bc.b[5] = t_bv;
  bias_concat_kernel<<<2, 768, 0, stream>>>(bc, bias2);

  // grid = (M/128)*(N/64) blocks, XCD-group-swizzled inside; NBq = N/256
  #define WGEMM(KV, Ap, ldav, Wp, bi, rs, CF, CB, M, N, rm, om, ac, rp)     \
    wgemm_kernel<KV><<<dim3(((M) / 128) * ((N) / 64)), 256, 0, stream>>>(   \
        Ap, ldav, Wp, bi, rs, CF, CB, N, (N) / 256, rm, om, ac, rp)

  // ---- spatial windowed attention (frames 0..7), M=32768 ----
  ln_norm_kernel<<<8192, 256, 0, stream>>>(query, 1, sln_g, sln_b, XA);
  WGEMM(256, XA, 256, pk_sqkv, bias2, nullptr, nullptr, QKV,
        32768, 768, 0, 2, 0, 0);
  spatial_attn_kernel<<<1024, 256, 0, stream>>>(QKV);
  WGEMM(256, QKV, 768, pk_swo, s_bo, query, P4, nullptr,
        32768, 256, 2, 1, 0, 0);
  copy_frame8_kernel<<<4096, 256, 0, stream>>>(query, P4);

  // ---- temporal RoPE attention, M=36864 ----
  ln_norm_kernel<<<9216, 256, 0, stream>>>(P4, 0, tln_g, tln_b, XA);
  WGEMM(256, XA, 256, pk_tqkv, bias2 + 768, nullptr, nullptr, QKV,
        36864, 768, 0, 2, 0, 1);
  temporal_attn_kernel<<<1152, 256, 0, stream>>>(QKV);
  WGEMM(256, QKV, 768, pk_two, t_bo, P4, out, nullptr,
        36864, 256, 1, 0, 0, 0);

  // ---- CLS frame spatial mean + broadcast (on out = x2) ----
  cls_sum_kernel<<<128, 256, 0, stream>>>(out, clsp);
  cls_bcast_kernel<<<32, 256, 0, stream>>>(out, clsp);

  // ---- FUSED MLP (ln + w1 + gelu + w2 + resid), in place on out ----
  mlp_fused_kernel<<<1152, 64, 0, stream>>>(out, pk_w1, b1, pk_w2, b2,
                                            mln_g, mln_b);
  #undef WGEMM
}

// Round 8
// 517.089 us; speedup vs baseline: 1.9026x; 1.9026x over previous
//
#include <hip/hip_runtime.h>
#include <math.h>

#define TQ_  9

typedef unsigned int   u32;
typedef unsigned short ushort_t;
typedef short bf16x8 __attribute__((ext_vector_type(8)));
typedef float f32x4  __attribute__((ext_vector_type(4)));

__device__ __forceinline__ float bs2f(ushort_t s) {
  return __uint_as_float(((u32)s) << 16);
}
__device__ __forceinline__ ushort_t f2bs(float x) {   // round-to-nearest-even
  u32 u = __float_as_uint(x);
  u32 r = (u + 0x7FFFu + ((u >> 16) & 1u)) >> 16;
  return (ushort_t)r;
}

// ---------------------------------------------------------------------------
// Weight PACK: W f32 [K][N] -> MFMA-frag-linear bf16 (A-operand layout).
// Frag group G = (j*(K/32) + kk)*64 + q*16 + ln holds 8 bf16:
//   element e: out-col n = j*16+ln, k = kk*32 + q*8 + e.
// pm=1 (Q/K weights): out-columns permuted within each 32-col head so RoPE
// pairs (d, d+16) sit at positions c, c^8 of a 16-col chunk.
// ---------------------------------------------------------------------------
struct TPA { const float* s[10]; ushort_t* d[10]; int K[10]; int N[10]; int pm[10]; };

__global__ __launch_bounds__(256)
void pack_all_kernel(TPA p) {
  int z = blockIdx.z;
  int K = p.K[z], N = p.N[z];
  int bn = blockIdx.x << 5, bk = blockIdx.y << 5;
  if (bn >= N || bk >= K) return;
  const float* W = p.s[z];
  ushort_t* pk = p.d[z];
  int pm = p.pm[z];
  __shared__ float t[32][33];                 // [k_local][n_local]
  int tid = threadIdx.x;
  int tx = tid & 31, ty = tid >> 5;
  #pragma unroll
  for (int r = 0; r < 4; ++r)
    t[ty + (r << 3)][tx] = W[(long)(bk + ty + (r << 3)) * N + bn + tx];
  __syncthreads();
  if (tid < 128) {
    int jl = tid >> 6, q = (tid >> 4) & 3, ln = tid & 15;
    int j = (bn >> 4) + jl, kk = bk >> 5;
    int colsrc = pm ? ((ln & 7) + (jl << 3) + ((ln & 8) << 1))
                    : ((jl << 4) + ln);
    long G = (((long)j * (K >> 5) + kk) << 6) + (q << 4) + ln;
    bf16x8 ov;
    #pragma unroll
    for (int e = 0; e < 8; ++e)
      ov[e] = (short)f2bs(t[(q << 3) + e][colsrc]);
    *(bf16x8*)(pk + (G << 3)) = ov;
  }
}

// concat 3 biases x 2 stages into f32 [2][768]; Q/K parts permuted to match
struct BC6 { const float* b[6]; };
__global__ __launch_bounds__(768)
void bias_concat_kernel(BC6 p, float* __restrict__ dst) {
  int z = blockIdx.x, n = threadIdx.x;
  int w = n >> 8, q = n & 255;
  int psrc = q;
  if (w < 2)
    psrc = (q & 0xE0) | (q & 7) | (((q >> 4) & 1) << 3) | (((q >> 3) & 1) << 4);
  dst[z * 768 + n] = p.b[z * 3 + w][psrc];
}

// ---------------------------------------------------------------------------
// LayerNorm materialize: one wave per row (4 rows/block), float4 loads.
// ---------------------------------------------------------------------------
__global__ __launch_bounds__(256)
void ln_norm_kernel(const float* __restrict__ src, int spatial,
                    const float* __restrict__ g, const float* __restrict__ b,
                    ushort_t* __restrict__ dst) {
  int row = blockIdx.x * 4 + (threadIdx.x >> 6);
  int lane = threadIdx.x & 63;
  long srow = row;
  if (spatial) {
    int bq = row >> 13, r = row & 8191;
    srow = ((long)(bq * TQ_ + (r >> 10)) << 10) + (r & 1023);
  }
  float4 v = ((const float4*)(src + srow * 256))[lane];
  float s  = v.x + v.y + v.z + v.w;
  float s2 = v.x * v.x + v.y * v.y + v.z * v.z + v.w * v.w;
  #pragma unroll
  for (int m = 32; m; m >>= 1) {
    s  += __shfl_xor(s,  m, 64);
    s2 += __shfl_xor(s2, m, 64);
  }
  float mean = s * (1.f / 256.f);
  float rstd = rsqrtf(s2 * (1.f / 256.f) - mean * mean + 1e-5f);
  float4 gv = ((const float4*)g)[lane];
  float4 bv = ((const float4*)b)[lane];
  ushort_t o[4];
  o[0] = f2bs((v.x - mean) * rstd * gv.x + bv.x);
  o[1] = f2bs((v.y - mean) * rstd * gv.y + bv.y);
  o[2] = f2bs((v.z - mean) * rstd * gv.z + bv.z);
  o[3] = f2bs((v.w - mean) * rstd * gv.w + bv.w);
  u32 lo = (u32)o[0] | ((u32)o[1] << 16);
  u32 hi = (u32)o[2] | ((u32)o[3] << 16);
  uint2 pk; pk.x = lo; pk.y = hi;
  *(uint2*)(dst + (long)row * 256 + lane * 4) = pk;
}

// ---------------------------------------------------------------------------
// Barrier-free register-streaming GEMM (no LDS), swapped operand order:
//   D = W_frag (A-op, n-rows) x X_frag (B-op, m-cols) -> lane-contiguous cols.
// (unchanged from round 5 — verified, handles the 4 attn-stage GEMMs)
// ---------------------------------------------------------------------------
template<int K>
__global__ __launch_bounds__(256, 4)
void wgemm_kernel(const ushort_t* __restrict__ A, int lda,
                  const ushort_t* __restrict__ packW,
                  const float* __restrict__ bias, const float* __restrict__ resid,
                  float* __restrict__ Cf, ushort_t* __restrict__ Cb,
                  int N, int NBq, int resid_mode, int out_mode, int act, int rope) {
  constexpr int K32 = K / 32;
  constexpr int AD = (K32 >= 4) ? 4 : K32;    // X prefetch depth (reg ring)
  constexpr int BD = 2;                       // W prefetch depth

  int tid = threadIdx.x;
  int wv = tid >> 6, lane = tid & 63;
  int ln = lane & 15, q4 = lane >> 4;

  // XCD-grouping decode
  int gid = blockIdx.x;
  int g = gid >> 5, r = gid & 31;
  int nq = (r >> 3) + ((g % NBq) << 2);
  int mb = ((g / NBq) << 3) + (r & 7);
  int m0 = mb << 7, n0 = nq << 6;

  const ushort_t* Ap = A + (long)(m0 + (wv << 5) + ln) * lda + (q4 << 3);
  long a16 = (long)lda << 4;                  // +16 rows
  const ushort_t* Bp = packW + (((long)(nq << 2) * K32) << 9) + (lane << 3);

  bf16x8 xr[AD][2];                           // X fragments (B-operand)
  bf16x8 wr[BD][4];                           // W fragments (A-operand)
  #pragma unroll
  for (int d = 0; d < BD; ++d)
    #pragma unroll
    for (int j = 0; j < 4; ++j)
      wr[d][j] = *(const bf16x8*)(Bp + (((long)j * K32 + d) << 9));
  #pragma unroll
  for (int d = 0; d < AD; ++d) {
    xr[d][0] = *(const bf16x8*)(Ap + d * 32);
    xr[d][1] = *(const bf16x8*)(Ap + a16 + d * 32);
  }

  f32x4 acc[2][4];
  #pragma unroll
  for (int i = 0; i < 2; ++i)
    #pragma unroll
    for (int j = 0; j < 4; ++j) acc[i][j] = 0.f;

  #pragma unroll
  for (int kk = 0; kk < K32; ++kk) {          // fully unrolled: static indices
    #pragma unroll
    for (int i = 0; i < 2; ++i)
      #pragma unroll
      for (int j = 0; j < 4; ++j)
        acc[i][j] = __builtin_amdgcn_mfma_f32_16x16x32_bf16(
            wr[kk % BD][j], xr[kk % AD][i], acc[i][j], 0, 0, 0);
    if (kk + AD < K32) {
      xr[kk % AD][0] = *(const bf16x8*)(Ap + (kk + AD) * 32);
      xr[kk % AD][1] = *(const bf16x8*)(Ap + a16 + (kk + AD) * 32);
    }
    if (kk + BD < K32) {
      #pragma unroll
      for (int j = 0; j < 4; ++j)
        wr[kk % BD][j] = *(const bf16x8*)(Bp + (((long)j * K32 + kk + BD) << 9));
    }
    __builtin_amdgcn_sched_barrier(0);        // pin prefetch distance
  }

  // ---- epilogue (all lane-contiguous: float4 / uint2) ----
  float4 bj[4];
  #pragma unroll
  for (int j = 0; j < 4; ++j)
    bj[j] = *(const float4*)(bias + n0 + (j << 4) + (q4 << 2));

  float cs_c[2][4], cs_s[2][4];
  if (rope) {
    int t = (m0 >> 10) % TQ_;
    #pragma unroll
    for (int p = 0; p < 2; ++p)
      #pragma unroll
      for (int r2 = 0; r2 < 4; ++r2) {
        float d = (float)(((q4 & 1) << 2) + r2 + (p << 3));
        float ang = (float)t * exp2f(d * -0.8304820237218406f);
        cs_c[p][r2] = cosf(ang);
        float s = sinf(ang);
        cs_s[p][r2] = (q4 & 2) ? s : -s;      // x1 lanes: -s, x2 lanes: +s
      }
  }

  #pragma unroll
  for (int i = 0; i < 2; ++i) {
    int m = m0 + (wv << 5) + (i << 4) + ln;   // per-lane output row
    long orow = m;
    if (out_mode == 1 || resid_mode == 2) {
      int bq = m >> 13, rr = m & 8191;
      orow = ((long)(bq * TQ_ + (rr >> 10)) << 10) + (rr & 1023);
    }
    #pragma unroll
    for (int j = 0; j < 4; ++j) {
      int n = n0 + (j << 4) + (q4 << 2);      // 4 consecutive cols per lane
      float v[4];
      #pragma unroll
      for (int r2 = 0; r2 < 4; ++r2) v[r2] = acc[i][j][r2] + bj[j][r2];
      if (rope && ((nq << 2) + j) < 32) {     // Q,K region (first 512 cols)
        #pragma unroll
        for (int r2 = 0; r2 < 4; ++r2) {
          float other = __shfl_xor(v[r2], 32, 64);
          v[r2] = v[r2] * cs_c[j & 1][r2] + other * cs_s[j & 1][r2];
        }
      }
      if (act) {
        #pragma unroll
        for (int r2 = 0; r2 < 4; ++r2) {
          float x = v[r2];
          v[r2] = 0.5f * x * (1.f + erff(x * 0.70710678118654752f));
        }
      }
      if (resid_mode == 1) {
        float4 rv = *(const float4*)(resid + (long)m * 256 + n);
        v[0] += rv.x; v[1] += rv.y; v[2] += rv.z; v[3] += rv.w;
      } else if (resid_mode == 2) {
        float4 rv = *(const float4*)(resid + orow * 256 + n);
        v[0] += rv.x; v[1] += rv.y; v[2] += rv.z; v[3] += rv.w;
      }
      if (out_mode == 2) {
        uint2 pk;
        pk.x = (u32)f2bs(v[0]) | ((u32)f2bs(v[1]) << 16);
        pk.y = (u32)f2bs(v[2]) | ((u32)f2bs(v[3]) << 16);
        *(uint2*)(Cb + (long)m * N + n) = pk;
      } else {
        float4 o4; o4.x = v[0]; o4.y = v[1]; o4.z = v[2]; o4.w = v[3];
        if (out_mode == 1) *(float4*)(Cf + orow * 256 + n) = o4;
        else               *(float4*)(Cf + (long)m * N + n) = o4;
      }
    }
  }
}

// ---------------------------------------------------------------------------
// FUSED MLP v2: out = x + (gelu(LN(x) @ W1 + b1) @ W2 + b2), in place.
// 256 threads (4 waves) per 32-row tile, 1152 blocks -> 4608 waves (18/CU
// work, 8 resident at 80 KB LDS x 2 blocks/CU). Round-6 failure was 1 wave
// per block (4.5 waves/CU, occupancy 7%): pure latency serialization.
// Phases (2 barriers):
//   LN  : waves split rows (8 rows/wave, 8 lanes/row, shfl_xor 1/2/4)
//         -> XL (16 KB, 16B-group rotation swizzle).
//   w1  : wave wv owns hid cols wv*256..+255 (4 chunks x 64 MFMA), gelu,
//         pack bf16 -> HLDS[32][1024] with granule XOR swizzle
//         off = row*1024 + ((col&~7) ^ ((row&7)<<3)) + (col&7)
//         (producer uint2 / consumer b128 share the involution; consumer
//         col-slice reads are conflict-free by construction).
//   w2  : wave wv owns out cols wv*64..+63: 32 k-steps x 4 j x 2 i MFMA
//         (acc[2][4] = 32 VGPR), frags from HLDS + L2-resident W2 pack.
// Epilogue: +b2 + resid(x), float4, in place (waves disjoint cols).
// ---------------------------------------------------------------------------
__device__ __forceinline__ int xl_off(int row, int col) {   // elems; XL 32x256
  return (row << 8) + (((((col >> 3) + row) & 31)) << 3) + (col & 7);
}
__device__ __forceinline__ int hlds_off(int row, int col) { // elems; 32x1024
  return (row << 10) + ((col & ~7) ^ ((row & 7) << 3)) + (col & 7);
}

__global__ __launch_bounds__(256, 2)
void mlp_fused_kernel(float* xio,                       // in/out (same buffer)
                      const ushort_t* __restrict__ W1p, // packed [1024][256]
                      const float* __restrict__ b1,
                      const ushort_t* __restrict__ W2p, // packed [256][1024]
                      const float* __restrict__ b2,
                      const float* __restrict__ g,
                      const float* __restrict__ be) {
  __shared__ ushort_t XL[8192];     // 16 KB normalized X tile
  __shared__ ushort_t HLDS[32768];  // 64 KB hid tile (bf16, swizzled)
  int tid = threadIdx.x;
  int wv = tid >> 6, lane = tid & 63;
  int ln = lane & 15, q4 = lane >> 4;
  int m0 = blockIdx.x << 5;

  // ---- LN: wave wv rows wv*8..+7; 8 lanes/row; lane cols p*4 + k*32 ----
  {
    int lrow = (wv << 3) + (lane >> 3);       // local row 0..31
    int p = lane & 7;
    const float* xr = xio + (long)(m0 + lrow) * 256 + (p << 2);
    float s = 0.f, s2 = 0.f;
    float4 vbuf[8];
    #pragma unroll
    for (int k = 0; k < 8; ++k) {
      float4 a = *(const float4*)(xr + (k << 5));
      vbuf[k] = a;
      s  += a.x + a.y + a.z + a.w;
      s2 += a.x*a.x + a.y*a.y + a.z*a.z + a.w*a.w;
    }
    s  += __shfl_xor(s,  1, 64);  s  += __shfl_xor(s,  2, 64);  s  += __shfl_xor(s,  4, 64);
    s2 += __shfl_xor(s2, 1, 64);  s2 += __shfl_xor(s2, 2, 64);  s2 += __shfl_xor(s2, 4, 64);
    float mean = s * (1.f / 256.f);
    float rstd = rsqrtf(s2 * (1.f / 256.f) - mean * mean + 1e-5f);
    #pragma unroll
    for (int k = 0; k < 8; ++k) {
      int col = (p << 2) + (k << 5);
      float4 gv = *(const float4*)(g + col);
      float4 bv = *(const float4*)(be + col);
      float4 a = vbuf[k];
      u32 lo = (u32)f2bs((a.x - mean) * rstd * gv.x + bv.x)
             | ((u32)f2bs((a.y - mean) * rstd * gv.y + bv.y) << 16);
      u32 hi = (u32)f2bs((a.z - mean) * rstd * gv.z + bv.z)
             | ((u32)f2bs((a.w - mean) * rstd * gv.w + bv.w) << 16);
      uint2 pk; pk.x = lo; pk.y = hi;
      *(uint2*)&XL[xl_off(lrow, col)] = pk;
    }
  }
  __syncthreads();

  // ---- w1 + gelu: wave wv -> hid chunks c = wv*4..+3 (64 cols each) ----
  #pragma unroll
  for (int cc = 0; cc < 4; ++cc) {
    int c = (wv << 2) + cc;
    f32x4 h[2][4];
    #pragma unroll
    for (int i = 0; i < 2; ++i)
      #pragma unroll
      for (int jj = 0; jj < 4; ++jj) h[i][jj] = 0.f;
    #pragma unroll
    for (int ks = 0; ks < 8; ++ks) {
      int col = (q4 << 3) + (ks << 5);
      bf16x8 xf0 = *(const bf16x8*)&XL[xl_off(ln, col)];
      bf16x8 xf1 = *(const bf16x8*)&XL[xl_off(16 + ln, col)];
      #pragma unroll
      for (int jj = 0; jj < 4; ++jj) {
        bf16x8 wf = *(const bf16x8*)(W1p +
            (((long)((c << 2) + jj) * 8 + ks) << 9) + (lane << 3));
        h[0][jj] = __builtin_amdgcn_mfma_f32_16x16x32_bf16(wf, xf0, h[0][jj], 0, 0, 0);
        h[1][jj] = __builtin_amdgcn_mfma_f32_16x16x32_bf16(wf, xf1, h[1][jj], 0, 0, 0);
      }
    }
    #pragma unroll
    for (int jj = 0; jj < 4; ++jj) {
      float4 b1v = *(const float4*)(b1 + (c << 6) + (jj << 4) + (q4 << 2));
      #pragma unroll
      for (int i = 0; i < 2; ++i) {
        float v[4];
        v[0] = h[i][jj][0] + b1v.x;  v[1] = h[i][jj][1] + b1v.y;
        v[2] = h[i][jj][2] + b1v.z;  v[3] = h[i][jj][3] + b1v.w;
        #pragma unroll
        for (int r = 0; r < 4; ++r)
          v[r] = 0.5f * v[r] * (1.f + erff(v[r] * 0.70710678118654752f));
        uint2 pk;
        pk.x = (u32)f2bs(v[0]) | ((u32)f2bs(v[1]) << 16);
        pk.y = (u32)f2bs(v[2]) | ((u32)f2bs(v[3]) << 16);
        int hcol = (c << 6) + (jj << 4) + (q4 << 2);
        *(uint2*)&HLDS[hlds_off((i << 4) + ln, hcol)] = pk;
      }
    }
  }
  __syncthreads();

  // ---- w2: wave wv -> out cols wv*64..+63 ----
  f32x4 acc[2][4];
  #pragma unroll
  for (int i = 0; i < 2; ++i)
    #pragma unroll
    for (int jl = 0; jl < 4; ++jl) acc[i][jl] = 0.f;

  #pragma unroll 4
  for (int kc = 0; kc < 32; ++kc) {
    int col = (kc << 5) + (q4 << 3);
    bf16x8 hb0 = *(const bf16x8*)&HLDS[hlds_off(ln, col)];
    bf16x8 hb1 = *(const bf16x8*)&HLDS[hlds_off(16 + ln, col)];
    #pragma unroll
    for (int jl = 0; jl < 4; ++jl) {
      bf16x8 wf = *(const bf16x8*)(W2p +
          (((long)((wv << 2) + jl) * 32 + kc) << 9) + (lane << 3));
      acc[0][jl] = __builtin_amdgcn_mfma_f32_16x16x32_bf16(wf, hb0, acc[0][jl], 0, 0, 0);
      acc[1][jl] = __builtin_amdgcn_mfma_f32_16x16x32_bf16(wf, hb1, acc[1][jl], 0, 0, 0);
    }
  }

  // ---- epilogue: +b2 +resid(x), float4 stores, in place ----
  #pragma unroll
  for (int i = 0; i < 2; ++i) {
    long ro = (long)(m0 + (i << 4) + ln) * 256;
    #pragma unroll
    for (int jl = 0; jl < 4; ++jl) {
      int n = ((wv << 2) + jl) * 16 + (q4 << 2);
      float4 rv = *(const float4*)(xio + ro + n);
      float4 bv = *(const float4*)(b2 + n);
      float4 o;
      o.x = acc[i][jl][0] + bv.x + rv.x;
      o.y = acc[i][jl][1] + bv.y + rv.y;
      o.z = acc[i][jl][2] + bv.z + rv.z;
      o.w = acc[i][jl][3] + bv.w + rv.w;
      *(float4*)(xio + ro + n) = o;
    }
  }
}

// ---------------------------------------------------------------------------
// Spatial 3x3 windowed attention on packed QKV [m][768] bf16.
// ---------------------------------------------------------------------------
__global__ __launch_bounds__(256)
void spatial_attn_kernel(ushort_t* __restrict__ qkv) {
  int gid = blockIdx.x * 256 + threadIdx.x;   // 262144
  int head = gid & 7, pixel = gid >> 3;
  int pix = pixel & 1023, bt = pixel >> 10;
  int y = pix >> 5, x = pix & 31;
  long rb = (long)bt << 10;
  const float scale = 0.17677669529663687f;   // 1/sqrt(32)

  float qf[32];
  long qoff = (long)pixel * 768 + head * 32;
  #pragma unroll
  for (int i = 0; i < 4; ++i) {
    bf16x8 t = *(const bf16x8*)(qkv + qoff + i * 8);
    #pragma unroll
    for (int e = 0; e < 8; ++e) qf[i * 8 + e] = bs2f((ushort_t)t[e]);
  }

  float s[9];
  bool val[9];
  #pragma unroll
  for (int n = 0; n < 9; ++n) {
    int yy = y + n / 3 - 1, xx = x + n % 3 - 1;
    bool ok = ((unsigned)yy < 32u) & ((unsigned)xx < 32u);
    val[n] = ok;
    float d = 0.f;
    if (ok) {
      long ko = (rb + (yy << 5) + xx) * 768 + 256 + head * 32;
      #pragma unroll
      for (int i = 0; i < 4; ++i) {
        bf16x8 t = *(const bf16x8*)(qkv + ko + i * 8);
        #pragma unroll
        for (int e = 0; e < 8; ++e) d += qf[i * 8 + e] * bs2f((ushort_t)t[e]);
      }
    }
    s[n] = d * scale;
  }
  float mx = -1e30f;
  #pragma unroll
  for (int n = 0; n < 9; ++n) if (val[n]) mx = fmaxf(mx, s[n]);
  float sum = 0.f;
  #pragma unroll
  for (int n = 0; n < 9; ++n) { s[n] = val[n] ? __expf(s[n] - mx) : 0.f; sum += s[n]; }
  float inv = 1.f / sum;

  float o[32];
  #pragma unroll
  for (int i = 0; i < 32; ++i) o[i] = 0.f;
  #pragma unroll
  for (int n = 0; n < 9; ++n) {
    if (val[n]) {
      int yy = y + n / 3 - 1, xx = x + n % 3 - 1;
      long vo = (rb + (yy << 5) + xx) * 768 + 512 + head * 32;
      #pragma unroll
      for (int i = 0; i < 4; ++i) {
        bf16x8 t = *(const bf16x8*)(qkv + vo + i * 8);
        #pragma unroll
        for (int e = 0; e < 8; ++e) o[i * 8 + e] += s[n] * bs2f((ushort_t)t[e]);
      }
    }
  }
  #pragma unroll
  for (int i = 0; i < 4; ++i) {
    bf16x8 t;
    #pragma unroll
    for (int e = 0; e < 8; ++e) t[e] = (short)f2bs(o[i * 8 + e] * inv);
    *(bf16x8*)(qkv + qoff + i * 8) = t;
  }
}

// ---------------------------------------------------------------------------
// Temporal attention (full 9x9; mask all-False). o over q in-place.
// ---------------------------------------------------------------------------
__global__ __launch_bounds__(256)
void temporal_attn_kernel(ushort_t* __restrict__ qkv) {
  int tid = threadIdx.x;
  int head = tid & 7, hwi = tid >> 3;
  int bi = blockIdx.x;                          // 1152 = 9 * 4 * 32
  int tq = bi >> 7;
  int rest = bi & 127;
  int b = rest >> 5, hwg = rest & 31;
  int hw = (hwg << 5) + hwi;
  long base = (long)(b * TQ_) * 1024 + hw;
  const float scale = 0.17677669529663687f;

  float qf[32];
  long qoff = (base + (long)tq * 1024) * 768 + head * 32;
  #pragma unroll
  for (int i = 0; i < 4; ++i) {
    bf16x8 t = *(const bf16x8*)(qkv + qoff + i * 8);
    #pragma unroll
    for (int e = 0; e < 8; ++e) qf[i * 8 + e] = bs2f((ushort_t)t[e]);
  }
  float s[9];
  #pragma unroll
  for (int tk = 0; tk < 9; ++tk) {
    long ko = (base + (long)tk * 1024) * 768 + 256 + head * 32;
    float d = 0.f;
    #pragma unroll
    for (int i = 0; i < 4; ++i) {
      bf16x8 t = *(const bf16x8*)(qkv + ko + i * 8);
      #pragma unroll
      for (int e = 0; e < 8; ++e) d += qf[i * 8 + e] * bs2f((ushort_t)t[e]);
    }
    s[tk] = d * scale;
  }
  float mx = s[0];
  #pragma unroll
  for (int tk = 1; tk < 9; ++tk) mx = fmaxf(mx, s[tk]);
  float sum = 0.f;
  #pragma unroll
  for (int tk = 0; tk < 9; ++tk) { s[tk] = __expf(s[tk] - mx); sum += s[tk]; }
  float inv = 1.f / sum;

  float o[32];
  #pragma unroll
  for (int i = 0; i < 32; ++i) o[i] = 0.f;
  #pragma unroll
  for (int tk = 0; tk < 9; ++tk) {
    long vo = (base + (long)tk * 1024) * 768 + 512 + head * 32;
    #pragma unroll
    for (int i = 0; i < 4; ++i) {
      bf16x8 t = *(const bf16x8*)(qkv + vo + i * 8);
      #pragma unroll
      for (int e = 0; e < 8; ++e) o[i * 8 + e] += s[tk] * bs2f((ushort_t)t[e]);
    }
  }
  #pragma unroll
  for (int i = 0; i < 4; ++i) {
    bf16x8 t;
    #pragma unroll
    for (int e = 0; e < 8; ++e) t[e] = (short)f2bs(o[i * 8 + e] * inv);
    *(bf16x8*)(qkv + qoff + i * 8) = t;
  }
}

// copy query frame 8 into x (f32); identical linear indices in both buffers
__global__ __launch_bounds__(256)
void copy_frame8_kernel(const float* __restrict__ qy, float* __restrict__ x) {
  long i = (long)blockIdx.x * 256 + threadIdx.x;
  int b = (int)(i >> 18);
  long rem = i & ((1L << 18) - 1);
  long gi = ((long)(b * TQ_ + 8) << 18) + rem;
  x[gi] = qy[gi];
}

// CLS frame mean over spatial: partial sums then broadcast (on f32 x)
__global__ __launch_bounds__(256)
void cls_sum_kernel(const float* __restrict__ x, float* __restrict__ partial) {
  int b = blockIdx.x >> 5, ch = blockIdx.x & 31;
  int d = threadIdx.x;
  long base = ((long)(b * TQ_) * 1024 + ch * 32) * 256 + d;
  float s = 0.f;
  for (int r = 0; r < 32; ++r) s += x[base + (long)r * 256];
  partial[(long)blockIdx.x * 256 + d] = s;
}

__global__ __launch_bounds__(256)
void cls_bcast_kernel(float* __restrict__ x, const float* __restrict__ partial) {
  int b = blockIdx.x >> 3, seg = blockIdx.x & 7;
  int d = threadIdx.x;
  float s = 0.f;
  for (int j = 0; j < 32; ++j) s += partial[(long)(b * 32 + j) * 256 + d];
  s *= (1.f / 1024.f);
  long base = ((long)(b * TQ_) * 1024 + seg * 128) * 256 + d;
  for (int r = 0; r < 128; ++r) x[base + (long)r * 256] = s;
}

// ---------------------------------------------------------------------------
extern "C" void kernel_launch(void* const* d_in, const int* in_sizes, int n_in,
                              void* d_out, int out_size, void* d_ws, size_t ws_size,
                              hipStream_t stream) {
  (void)in_sizes; (void)n_in; (void)out_size; (void)ws_size;
  const float* query = (const float*)d_in[0];
  const float* sln_g = (const float*)d_in[3];
  const float* sln_b = (const float*)d_in[4];
  const float* s_wq  = (const float*)d_in[5];
  const float* s_bq  = (const float*)d_in[6];
  const float* s_wk  = (const float*)d_in[7];
  const float* s_bk  = (const float*)d_in[8];
  const float* s_wv  = (const float*)d_in[9];
  const float* s_bv  = (const float*)d_in[10];
  const float* s_wo  = (const float*)d_in[11];
  const float* s_bo  = (const float*)d_in[12];
  const float* tln_g = (const float*)d_in[13];
  const float* tln_b = (const float*)d_in[14];
  const float* t_wq  = (const float*)d_in[15];
  const float* t_bq  = (const float*)d_in[16];
  const float* t_wk  = (const float*)d_in[17];
  const float* t_bk  = (const float*)d_in[18];
  const float* t_wv  = (const float*)d_in[19];
  const float* t_bv  = (const float*)d_in[20];
  const float* t_wo  = (const float*)d_in[21];
  const float* t_bo  = (const float*)d_in[22];
  const float* mln_g = (const float*)d_in[23];
  const float* mln_b = (const float*)d_in[24];
  const float* w1    = (const float*)d_in[25];
  const float* b1    = (const float*)d_in[26];
  const float* w2    = (const float*)d_in[27];
  const float* b2    = (const float*)d_in[28];
  float* out = (float*)d_out;

  // ---- workspace ----
  const long RB = 36864L * 256;
  ushort_t* XA  = (ushort_t*)d_ws;          // RB bf16
  ushort_t* QKV = XA + RB;                  // 3*RB bf16, rows of 768
  float*    P4  = (float*)(QKV + 3 * RB);   // RB f32
  ushort_t* wt  = (ushort_t*)(P4 + RB);     // 2 MB packed weights
  float* bias2  = (float*)(wt + 1048576);   // 2x768 f32
  float* clsp   = bias2 + 1536;             // 128*256 f32

  ushort_t* pk_sqkv = wt;                   // packed [768][256]
  ushort_t* pk_tqkv = wt + 196608;          // packed [768][256]
  ushort_t* pk_swo  = wt + 393216;          // packed [256][256]
  ushort_t* pk_two  = wt + 458752;          // packed [256][256]
  ushort_t* pk_w1   = wt + 524288;          // packed [1024][256]
  ushort_t* pk_w2   = wt + 786432;          // packed [256][1024]

  // ---- weight / bias prep (one pack dispatch) ----
  TPA tp;
  tp.s[0] = s_wq; tp.d[0] = pk_sqkv;          tp.K[0] = 256;  tp.N[0] = 256;  tp.pm[0] = 1;
  tp.s[1] = s_wk; tp.d[1] = pk_sqkv + 65536;  tp.K[1] = 256;  tp.N[1] = 256;  tp.pm[1] = 1;
  tp.s[2] = s_wv; tp.d[2] = pk_sqkv + 131072; tp.K[2] = 256;  tp.N[2] = 256;  tp.pm[2] = 0;
  tp.s[3] = t_wq; tp.d[3] = pk_tqkv;          tp.K[3] = 256;  tp.N[3] = 256;  tp.pm[3] = 1;
  tp.s[4] = t_wk; tp.d[4] = pk_tqkv + 65536;  tp.K[4] = 256;  tp.N[4] = 256;  tp.pm[4] = 1;
  tp.s[5] = t_wv; tp.d[5] = pk_tqkv + 131072; tp.K[5] = 256;  tp.N[5] = 256;  tp.pm[5] = 0;
  tp.s[6] = s_wo; tp.d[6] = pk_swo;           tp.K[6] = 256;  tp.N[6] = 256;  tp.pm[6] = 0;
  tp.s[7] = t_wo; tp.d[7] = pk_two;           tp.K[7] = 256;  tp.N[7] = 256;  tp.pm[7] = 0;
  tp.s[8] = w1;   tp.d[8] = pk_w1;            tp.K[8] = 256;  tp.N[8] = 1024; tp.pm[8] = 0;
  tp.s[9] = w2;   tp.d[9] = pk_w2;            tp.K[9] = 1024; tp.N[9] = 256;  tp.pm[9] = 0;
  pack_all_kernel<<<dim3(32, 32, 10), 256, 0, stream>>>(tp);
  BC6 bc;
  bc.b[0] = s_bq; bc.b[1] = s_bk; bc.b[2] = s_bv;
  bc.b[3] = t_bq; bc.b[4] = t_bk; bc.b[5] = t_bv;
  bias_concat_kernel<<<2, 768, 0, stream>>>(bc, bias2);

  // grid = (M/128)*(N/64) blocks, XCD-group-swizzled inside; NBq = N/256
  #define WGEMM(KV, Ap, ldav, Wp, bi, rs, CF, CB, M, N, rm, om, ac, rp)     \
    wgemm_kernel<KV><<<dim3(((M) / 128) * ((N) / 64)), 256, 0, stream>>>(   \
        Ap, ldav, Wp, bi, rs, CF, CB, N, (N) / 256, rm, om, ac, rp)

  // ---- spatial windowed attention (frames 0..7), M=32768 ----
  ln_norm_kernel<<<8192, 256, 0, stream>>>(query, 1, sln_g, sln_b, XA);
  WGEMM(256, XA, 256, pk_sqkv, bias2, nullptr, nullptr, QKV,
        32768, 768, 0, 2, 0, 0);
  spatial_attn_kernel<<<1024, 256, 0, stream>>>(QKV);
  WGEMM(256, QKV, 768, pk_swo, s_bo, query, P4, nullptr,
        32768, 256, 2, 1, 0, 0);
  copy_frame8_kernel<<<4096, 256, 0, stream>>>(query, P4);

  // ---- temporal RoPE attention, M=36864 ----
  ln_norm_kernel<<<9216, 256, 0, stream>>>(P4, 0, tln_g, tln_b, XA);
  WGEMM(256, XA, 256, pk_tqkv, bias2 + 768, nullptr, nullptr, QKV,
        36864, 768, 0, 2, 0, 1);
  temporal_attn_kernel<<<1152, 256, 0, stream>>>(QKV);
  WGEMM(256, QKV, 768, pk_two, t_bo, P4, out, nullptr,
        36864, 256, 1, 0, 0, 0);

  // ---- CLS frame spatial mean + broadcast (on out = x2) ----
  cls_sum_kernel<<<128, 256, 0, stream>>>(out, clsp);
  cls_bcast_kernel<<<32, 256, 0, stream>>>(out, clsp);

  // ---- FUSED MLP v2 (ln + w1 + gelu + w2 + resid), in place on out ----
  mlp_fused_kernel<<<1152, 256, 0, stream>>>(out, pk_w1, b1, pk_w2, b2,
                                             mln_g, mln_b);
  #undef WGEMM
}

// Round 9
// 505.035 us; speedup vs baseline: 1.9480x; 1.0239x over previous
//
#include <hip/hip_runtime.h>
#include <math.h>

#define TQ_  9

typedef unsigned int   u32;
typedef unsigned short ushort_t;
typedef short bf16x8 __attribute__((ext_vector_type(8)));
typedef float f32x4  __attribute__((ext_vector_type(4)));

__device__ __forceinline__ float bs2f(ushort_t s) {
  return __uint_as_float(((u32)s) << 16);
}
__device__ __forceinline__ ushort_t f2bs(float x) {   // round-to-nearest-even
  u32 u = __float_as_uint(x);
  u32 r = (u + 0x7FFFu + ((u >> 16) & 1u)) >> 16;
  return (ushort_t)r;
}

// fast gelu: 0.5x(1+erf(x/sqrt2)), erf via Abramowitz-Stegun 7.1.26
// (|abs err| < 1.5e-7, far below bf16 rounding). ~15 VALU ops vs erff's ~30+.
__device__ __forceinline__ float gelu_f(float x) {
  float z = x * 0.70710678118654752f;
  float a = fabsf(z);
  float t = __builtin_amdgcn_rcpf(1.f + 0.3275911f * a);
  float poly = t * (0.254829592f + t * (-0.284496736f +
               t * (1.421413741f + t * (-1.453152027f + t * 1.061405429f))));
  float erfv = 1.f - poly * __expf(-z * z);
  erfv = (z < 0.f) ? -erfv : erfv;
  return 0.5f * x * (1.f + erfv);
}

// ---------------------------------------------------------------------------
// Weight PACK: W f32 [K][N] -> MFMA-frag-linear bf16 (A-operand layout).
// Frag group G = (j*(K/32) + kk)*64 + q*16 + ln holds 8 bf16:
//   element e: out-col n = j*16+ln, k = kk*32 + q*8 + e.
// pm=1 (Q/K weights): out-columns permuted within each 32-col head so RoPE
// pairs (d, d+16) sit at positions c, c^8 of a 16-col chunk.
// ---------------------------------------------------------------------------
struct TPA { const float* s[10]; ushort_t* d[10]; int K[10]; int N[10]; int pm[10]; };

__global__ __launch_bounds__(256)
void pack_all_kernel(TPA p) {
  int z = blockIdx.z;
  int K = p.K[z], N = p.N[z];
  int bn = blockIdx.x << 5, bk = blockIdx.y << 5;
  if (bn >= N || bk >= K) return;
  const float* W = p.s[z];
  ushort_t* pk = p.d[z];
  int pm = p.pm[z];
  __shared__ float t[32][33];                 // [k_local][n_local]
  int tid = threadIdx.x;
  int tx = tid & 31, ty = tid >> 5;
  #pragma unroll
  for (int r = 0; r < 4; ++r)
    t[ty + (r << 3)][tx] = W[(long)(bk + ty + (r << 3)) * N + bn + tx];
  __syncthreads();
  if (tid < 128) {
    int jl = tid >> 6, q = (tid >> 4) & 3, ln = tid & 15;
    int j = (bn >> 4) + jl, kk = bk >> 5;
    int colsrc = pm ? ((ln & 7) + (jl << 3) + ((ln & 8) << 1))
                    : ((jl << 4) + ln);
    long G = (((long)j * (K >> 5) + kk) << 6) + (q << 4) + ln;
    bf16x8 ov;
    #pragma unroll
    for (int e = 0; e < 8; ++e)
      ov[e] = (short)f2bs(t[(q << 3) + e][colsrc]);
    *(bf16x8*)(pk + (G << 3)) = ov;
  }
}

// concat 3 biases x 2 stages into f32 [2][768]; Q/K parts permuted to match
struct BC6 { const float* b[6]; };
__global__ __launch_bounds__(768)
void bias_concat_kernel(BC6 p, float* __restrict__ dst) {
  int z = blockIdx.x, n = threadIdx.x;
  int w = n >> 8, q = n & 255;
  int psrc = q;
  if (w < 2)
    psrc = (q & 0xE0) | (q & 7) | (((q >> 4) & 1) << 3) | (((q >> 3) & 1) << 4);
  dst[z * 768 + n] = p.b[z * 3 + w][psrc];
}

// ---------------------------------------------------------------------------
// LayerNorm materialize: one wave per row (4 rows/block), float4 loads.
// ---------------------------------------------------------------------------
__global__ __launch_bounds__(256)
void ln_norm_kernel(const float* __restrict__ src, int spatial,
                    const float* __restrict__ g, const float* __restrict__ b,
                    ushort_t* __restrict__ dst) {
  int row = blockIdx.x * 4 + (threadIdx.x >> 6);
  int lane = threadIdx.x & 63;
  long srow = row;
  if (spatial) {
    int bq = row >> 13, r = row & 8191;
    srow = ((long)(bq * TQ_ + (r >> 10)) << 10) + (r & 1023);
  }
  float4 v = ((const float4*)(src + srow * 256))[lane];
  float s  = v.x + v.y + v.z + v.w;
  float s2 = v.x * v.x + v.y * v.y + v.z * v.z + v.w * v.w;
  #pragma unroll
  for (int m = 32; m; m >>= 1) {
    s  += __shfl_xor(s,  m, 64);
    s2 += __shfl_xor(s2, m, 64);
  }
  float mean = s * (1.f / 256.f);
  float rstd = rsqrtf(s2 * (1.f / 256.f) - mean * mean + 1e-5f);
  float4 gv = ((const float4*)g)[lane];
  float4 bv = ((const float4*)b)[lane];
  ushort_t o[4];
  o[0] = f2bs((v.x - mean) * rstd * gv.x + bv.x);
  o[1] = f2bs((v.y - mean) * rstd * gv.y + bv.y);
  o[2] = f2bs((v.z - mean) * rstd * gv.z + bv.z);
  o[3] = f2bs((v.w - mean) * rstd * gv.w + bv.w);
  u32 lo = (u32)o[0] | ((u32)o[1] << 16);
  u32 hi = (u32)o[2] | ((u32)o[3] << 16);
  uint2 pk; pk.x = lo; pk.y = hi;
  *(uint2*)(dst + (long)row * 256 + lane * 4) = pk;
}

// ---------------------------------------------------------------------------
// Barrier-free register-streaming GEMM (no LDS), swapped operand order:
//   D = W_frag (A-op, n-rows) x X_frag (B-op, m-cols) -> lane-contiguous cols.
// (unchanged from round 5 — verified, handles the 4 attn-stage GEMMs)
// ---------------------------------------------------------------------------
template<int K>
__global__ __launch_bounds__(256, 4)
void wgemm_kernel(const ushort_t* __restrict__ A, int lda,
                  const ushort_t* __restrict__ packW,
                  const float* __restrict__ bias, const float* __restrict__ resid,
                  float* __restrict__ Cf, ushort_t* __restrict__ Cb,
                  int N, int NBq, int resid_mode, int out_mode, int act, int rope) {
  constexpr int K32 = K / 32;
  constexpr int AD = (K32 >= 4) ? 4 : K32;    // X prefetch depth (reg ring)
  constexpr int BD = 2;                       // W prefetch depth

  int tid = threadIdx.x;
  int wv = tid >> 6, lane = tid & 63;
  int ln = lane & 15, q4 = lane >> 4;

  // XCD-grouping decode
  int gid = blockIdx.x;
  int g = gid >> 5, r = gid & 31;
  int nq = (r >> 3) + ((g % NBq) << 2);
  int mb = ((g / NBq) << 3) + (r & 7);
  int m0 = mb << 7, n0 = nq << 6;

  const ushort_t* Ap = A + (long)(m0 + (wv << 5) + ln) * lda + (q4 << 3);
  long a16 = (long)lda << 4;                  // +16 rows
  const ushort_t* Bp = packW + (((long)(nq << 2) * K32) << 9) + (lane << 3);

  bf16x8 xr[AD][2];                           // X fragments (B-operand)
  bf16x8 wr[BD][4];                           // W fragments (A-operand)
  #pragma unroll
  for (int d = 0; d < BD; ++d)
    #pragma unroll
    for (int j = 0; j < 4; ++j)
      wr[d][j] = *(const bf16x8*)(Bp + (((long)j * K32 + d) << 9));
  #pragma unroll
  for (int d = 0; d < AD; ++d) {
    xr[d][0] = *(const bf16x8*)(Ap + d * 32);
    xr[d][1] = *(const bf16x8*)(Ap + a16 + d * 32);
  }

  f32x4 acc[2][4];
  #pragma unroll
  for (int i = 0; i < 2; ++i)
    #pragma unroll
    for (int j = 0; j < 4; ++j) acc[i][j] = 0.f;

  #pragma unroll
  for (int kk = 0; kk < K32; ++kk) {          // fully unrolled: static indices
    #pragma unroll
    for (int i = 0; i < 2; ++i)
      #pragma unroll
      for (int j = 0; j < 4; ++j)
        acc[i][j] = __builtin_amdgcn_mfma_f32_16x16x32_bf16(
            wr[kk % BD][j], xr[kk % AD][i], acc[i][j], 0, 0, 0);
    if (kk + AD < K32) {
      xr[kk % AD][0] = *(const bf16x8*)(Ap + (kk + AD) * 32);
      xr[kk % AD][1] = *(const bf16x8*)(Ap + a16 + (kk + AD) * 32);
    }
    if (kk + BD < K32) {
      #pragma unroll
      for (int j = 0; j < 4; ++j)
        wr[kk % BD][j] = *(const bf16x8*)(Bp + (((long)j * K32 + kk + BD) << 9));
    }
    __builtin_amdgcn_sched_barrier(0);        // pin prefetch distance
  }

  // ---- epilogue (all lane-contiguous: float4 / uint2) ----
  float4 bj[4];
  #pragma unroll
  for (int j = 0; j < 4; ++j)
    bj[j] = *(const float4*)(bias + n0 + (j << 4) + (q4 << 2));

  float cs_c[2][4], cs_s[2][4];
  if (rope) {
    int t = (m0 >> 10) % TQ_;
    #pragma unroll
    for (int p = 0; p < 2; ++p)
      #pragma unroll
      for (int r2 = 0; r2 < 4; ++r2) {
        float d = (float)(((q4 & 1) << 2) + r2 + (p << 3));
        float ang = (float)t * exp2f(d * -0.8304820237218406f);
        cs_c[p][r2] = cosf(ang);
        float s = sinf(ang);
        cs_s[p][r2] = (q4 & 2) ? s : -s;      // x1 lanes: -s, x2 lanes: +s
      }
  }

  #pragma unroll
  for (int i = 0; i < 2; ++i) {
    int m = m0 + (wv << 5) + (i << 4) + ln;   // per-lane output row
    long orow = m;
    if (out_mode == 1 || resid_mode == 2) {
      int bq = m >> 13, rr = m & 8191;
      orow = ((long)(bq * TQ_ + (rr >> 10)) << 10) + (rr & 1023);
    }
    #pragma unroll
    for (int j = 0; j < 4; ++j) {
      int n = n0 + (j << 4) + (q4 << 2);      // 4 consecutive cols per lane
      float v[4];
      #pragma unroll
      for (int r2 = 0; r2 < 4; ++r2) v[r2] = acc[i][j][r2] + bj[j][r2];
      if (rope && ((nq << 2) + j) < 32) {     // Q,K region (first 512 cols)
        #pragma unroll
        for (int r2 = 0; r2 < 4; ++r2) {
          float other = __shfl_xor(v[r2], 32, 64);
          v[r2] = v[r2] * cs_c[j & 1][r2] + other * cs_s[j & 1][r2];
        }
      }
      if (act) {
        #pragma unroll
        for (int r2 = 0; r2 < 4; ++r2) v[r2] = gelu_f(v[r2]);
      }
      if (resid_mode == 1) {
        float4 rv = *(const float4*)(resid + (long)m * 256 + n);
        v[0] += rv.x; v[1] += rv.y; v[2] += rv.z; v[3] += rv.w;
      } else if (resid_mode == 2) {
        float4 rv = *(const float4*)(resid + orow * 256 + n);
        v[0] += rv.x; v[1] += rv.y; v[2] += rv.z; v[3] += rv.w;
      }
      if (out_mode == 2) {
        uint2 pk;
        pk.x = (u32)f2bs(v[0]) | ((u32)f2bs(v[1]) << 16);
        pk.y = (u32)f2bs(v[2]) | ((u32)f2bs(v[3]) << 16);
        *(uint2*)(Cb + (long)m * N + n) = pk;
      } else {
        float4 o4; o4.x = v[0]; o4.y = v[1]; o4.z = v[2]; o4.w = v[3];
        if (out_mode == 1) *(float4*)(Cf + orow * 256 + n) = o4;
        else               *(float4*)(Cf + (long)m * N + n) = o4;
      }
    }
  }
}

// ---------------------------------------------------------------------------
// FUSED MLP v3: out = x + (gelu(LN(x) @ W1 + b1) @ W2 + b2), in place.
// 64 rows/block (576 blocks): halves the per-block full-W1+W2 L2 read
// (1.15 GB -> 576 MB, the round-8 floor). 4 waves; hid processed in 4
// QUARTERS of 256 cols so HLDS is 32 KB; XL 32 KB -> 64 KB total ->
// 2 blocks/CU. Fast A&S erf gelu (~15 ops vs erff ~30+). Weight frags
// double-buffered in registers (load-next-before-compute, no WAR) with
// sched_barrier(0) per k-step to pin the prefetch distance (round-4/5
// lesson: hipcc sinks loads otherwise).
// Phases: LN -> sync -> 4x { w1(quarter)+gelu->HLDS -> sync -> w2 partial
// accumulate -> sync } -> epilogue (+b2 +x, float4, in place).
// ---------------------------------------------------------------------------
__device__ __forceinline__ int tl_off(int row, int col) {   // 256-col bf16 tile
  return (row << 8) + (((((col >> 3) + row) & 31)) << 3) + (col & 7);
}

__global__ __launch_bounds__(256, 2)
void mlp_fused_kernel(float* xio,                       // in/out (same buffer)
                      const ushort_t* __restrict__ W1p, // packed [1024][256]
                      const float* __restrict__ b1,
                      const ushort_t* __restrict__ W2p, // packed [256][1024]
                      const float* __restrict__ b2,
                      const float* __restrict__ g,
                      const float* __restrict__ be) {
  __shared__ ushort_t XL[16384];    // 32 KB: 64x256 normalized X (swizzled)
  __shared__ ushort_t HLDS[16384];  // 32 KB: 64x256 hid quarter (swizzled)
  int tid = threadIdx.x;
  int wv = tid >> 6, lane = tid & 63;
  int ln = lane & 15, q4 = lane >> 4;
  int m0 = blockIdx.x << 6;                   // 64 rows

  // ---- LN: 16 rows/wave, 4 lanes/row (shfl_xor 1,2), 64 floats/lane ----
  {
    int lrow = (wv << 4) + (lane >> 2);       // local row 0..63
    int p = lane & 3;
    const float* xr = xio + (long)(m0 + lrow) * 256 + (p << 2);
    float s = 0.f, s2 = 0.f;
    float4 vbuf[16];
    #pragma unroll
    for (int k = 0; k < 16; ++k) {
      float4 a = *(const float4*)(xr + (k << 4));
      vbuf[k] = a;
      s  += a.x + a.y + a.z + a.w;
      s2 += a.x*a.x + a.y*a.y + a.z*a.z + a.w*a.w;
    }
    s  += __shfl_xor(s,  1, 64);  s  += __shfl_xor(s,  2, 64);
    s2 += __shfl_xor(s2, 1, 64);  s2 += __shfl_xor(s2, 2, 64);
    float mean = s * (1.f / 256.f);
    float rstd = rsqrtf(s2 * (1.f / 256.f) - mean * mean + 1e-5f);
    #pragma unroll
    for (int k = 0; k < 16; ++k) {
      int col = (p << 2) + (k << 4);
      float4 gv = *(const float4*)(g + col);
      float4 bv = *(const float4*)(be + col);
      float4 a = vbuf[k];
      u32 lo = (u32)f2bs((a.x - mean) * rstd * gv.x + bv.x)
             | ((u32)f2bs((a.y - mean) * rstd * gv.y + bv.y) << 16);
      u32 hi = (u32)f2bs((a.z - mean) * rstd * gv.z + bv.z)
             | ((u32)f2bs((a.w - mean) * rstd * gv.w + bv.w) << 16);
      uint2 pk; pk.x = lo; pk.y = hi;
      *(uint2*)&XL[tl_off(lrow, col)] = pk;
    }
  }
  __syncthreads();

  f32x4 acc[4][4];                            // out acc: 4 i x 4 jl (64 VGPR)
  #pragma unroll
  for (int i = 0; i < 4; ++i)
    #pragma unroll
    for (int jl = 0; jl < 4; ++jl) acc[i][jl] = 0.f;

  #pragma unroll 1
  for (int q = 0; q < 4; ++q) {               // hid quarters of 256 cols
    // ---- w1: wave wv -> global 64-col chunk c = q*4+wv ----
    {
      int c = (q << 2) + wv;
      f32x4 h[4][4];
      #pragma unroll
      for (int i = 0; i < 4; ++i)
        #pragma unroll
        for (int jj = 0; jj < 4; ++jj) h[i][jj] = 0.f;

      bf16x8 wf[2][4];
      #pragma unroll
      for (int jj = 0; jj < 4; ++jj)
        wf[0][jj] = *(const bf16x8*)(W1p + (((long)((c << 2) + jj) * 8) << 9) + (lane << 3));
      #pragma unroll
      for (int ks = 0; ks < 8; ++ks) {
        if (ks + 1 < 8) {                     // prefetch next (no WAR: other buf)
          #pragma unroll
          for (int jj = 0; jj < 4; ++jj)
            wf[(ks + 1) & 1][jj] = *(const bf16x8*)(W1p +
                (((long)((c << 2) + jj) * 8 + ks + 1) << 9) + (lane << 3));
        }
        int col = (q4 << 3) + (ks << 5);
        bf16x8 xf[4];
        #pragma unroll
        for (int i = 0; i < 4; ++i)
          xf[i] = *(const bf16x8*)&XL[tl_off((i << 4) + ln, col)];
        #pragma unroll
        for (int jj = 0; jj < 4; ++jj)
          #pragma unroll
          for (int i = 0; i < 4; ++i)
            h[i][jj] = __builtin_amdgcn_mfma_f32_16x16x32_bf16(
                wf[ks & 1][jj], xf[i], h[i][jj], 0, 0, 0);
        __builtin_amdgcn_sched_barrier(0);
      }
      // +b1, fast gelu, pack -> HLDS (local col = wv*64 + jj*16 + q4*4)
      #pragma unroll
      for (int jj = 0; jj < 4; ++jj) {
        float4 b1v = *(const float4*)(b1 + (c << 6) + (jj << 4) + (q4 << 2));
        #pragma unroll
        for (int i = 0; i < 4; ++i) {
          float v[4];
          v[0] = gelu_f(h[i][jj][0] + b1v.x);
          v[1] = gelu_f(h[i][jj][1] + b1v.y);
          v[2] = gelu_f(h[i][jj][2] + b1v.z);
          v[3] = gelu_f(h[i][jj][3] + b1v.w);
          uint2 pk;
          pk.x = (u32)f2bs(v[0]) | ((u32)f2bs(v[1]) << 16);
          pk.y = (u32)f2bs(v[2]) | ((u32)f2bs(v[3]) << 16);
          *(uint2*)&HLDS[tl_off((i << 4) + ln, (wv << 6) + (jj << 4) + (q4 << 2))] = pk;
        }
      }
    }
    __syncthreads();

    // ---- w2 partial: wave wv -> out cols wv*64..+63; k = quarter cols ----
    {
      bf16x8 wf2[2][4];
      #pragma unroll
      for (int jl = 0; jl < 4; ++jl)
        wf2[0][jl] = *(const bf16x8*)(W2p +
            (((long)((wv << 2) + jl) * 32 + (q << 3)) << 9) + (lane << 3));
      #pragma unroll
      for (int kc = 0; kc < 8; ++kc) {
        if (kc + 1 < 8) {
          #pragma unroll
          for (int jl = 0; jl < 4; ++jl)
            wf2[(kc + 1) & 1][jl] = *(const bf16x8*)(W2p +
                (((long)((wv << 2) + jl) * 32 + (q << 3) + kc + 1) << 9) + (lane << 3));
        }
        int col = (kc << 5) + (q4 << 3);
        bf16x8 hb[4];
        #pragma unroll
        for (int i = 0; i < 4; ++i)
          hb[i] = *(const bf16x8*)&HLDS[tl_off((i << 4) + ln, col)];
        #pragma unroll
        for (int jl = 0; jl < 4; ++jl)
          #pragma unroll
          for (int i = 0; i < 4; ++i)
            acc[i][jl] = __builtin_amdgcn_mfma_f32_16x16x32_bf16(
                wf2[kc & 1][jl], hb[i], acc[i][jl], 0, 0, 0);
        __builtin_amdgcn_sched_barrier(0);
      }
    }
    __syncthreads();                          // before next quarter overwrites HLDS
  }

  // ---- epilogue: +b2 +resid(x), float4 stores, in place ----
  #pragma unroll
  for (int i = 0; i < 4; ++i) {
    long ro = (long)(m0 + (i << 4) + ln) * 256;
    #pragma unroll
    for (int jl = 0; jl < 4; ++jl) {
      int n = ((wv << 2) + jl) * 16 + (q4 << 2);
      float4 rv = *(const float4*)(xio + ro + n);
      float4 bv = *(const float4*)(b2 + n);
      float4 o;
      o.x = acc[i][jl][0] + bv.x + rv.x;
      o.y = acc[i][jl][1] + bv.y + rv.y;
      o.z = acc[i][jl][2] + bv.z + rv.z;
      o.w = acc[i][jl][3] + bv.w + rv.w;
      *(float4*)(xio + ro + n) = o;
    }
  }
}

// ---------------------------------------------------------------------------
// Spatial 3x3 windowed attention on packed QKV [m][768] bf16.
// ---------------------------------------------------------------------------
__global__ __launch_bounds__(256)
void spatial_attn_kernel(ushort_t* __restrict__ qkv) {
  int gid = blockIdx.x * 256 + threadIdx.x;   // 262144
  int head = gid & 7, pixel = gid >> 3;
  int pix = pixel & 1023, bt = pixel >> 10;
  int y = pix >> 5, x = pix & 31;
  long rb = (long)bt << 10;
  const float scale = 0.17677669529663687f;   // 1/sqrt(32)

  float qf[32];
  long qoff = (long)pixel * 768 + head * 32;
  #pragma unroll
  for (int i = 0; i < 4; ++i) {
    bf16x8 t = *(const bf16x8*)(qkv + qoff + i * 8);
    #pragma unroll
    for (int e = 0; e < 8; ++e) qf[i * 8 + e] = bs2f((ushort_t)t[e]);
  }

  float s[9];
  bool val[9];
  #pragma unroll
  for (int n = 0; n < 9; ++n) {
    int yy = y + n / 3 - 1, xx = x + n % 3 - 1;
    bool ok = ((unsigned)yy < 32u) & ((unsigned)xx < 32u);
    val[n] = ok;
    float d = 0.f;
    if (ok) {
      long ko = (rb + (yy << 5) + xx) * 768 + 256 + head * 32;
      #pragma unroll
      for (int i = 0; i < 4; ++i) {
        bf16x8 t = *(const bf16x8*)(qkv + ko + i * 8);
        #pragma unroll
        for (int e = 0; e < 8; ++e) d += qf[i * 8 + e] * bs2f((ushort_t)t[e]);
      }
    }
    s[n] = d * scale;
  }
  float mx = -1e30f;
  #pragma unroll
  for (int n = 0; n < 9; ++n) if (val[n]) mx = fmaxf(mx, s[n]);
  float sum = 0.f;
  #pragma unroll
  for (int n = 0; n < 9; ++n) { s[n] = val[n] ? __expf(s[n] - mx) : 0.f; sum += s[n]; }
  float inv = 1.f / sum;

  float o[32];
  #pragma unroll
  for (int i = 0; i < 32; ++i) o[i] = 0.f;
  #pragma unroll
  for (int n = 0; n < 9; ++n) {
    if (val[n]) {
      int yy = y + n / 3 - 1, xx = x + n % 3 - 1;
      long vo = (rb + (yy << 5) + xx) * 768 + 512 + head * 32;
      #pragma unroll
      for (int i = 0; i < 4; ++i) {
        bf16x8 t = *(const bf16x8*)(qkv + vo + i * 8);
        #pragma unroll
        for (int e = 0; e < 8; ++e) o[i * 8 + e] += s[n] * bs2f((ushort_t)t[e]);
      }
    }
  }
  #pragma unroll
  for (int i = 0; i < 4; ++i) {
    bf16x8 t;
    #pragma unroll
    for (int e = 0; e < 8; ++e) t[e] = (short)f2bs(o[i * 8 + e] * inv);
    *(bf16x8*)(qkv + qoff + i * 8) = t;
  }
}

// ---------------------------------------------------------------------------
// Temporal attention (full 9x9; mask all-False). o over q in-place.
// ---------------------------------------------------------------------------
__global__ __launch_bounds__(256)
void temporal_attn_kernel(ushort_t* __restrict__ qkv) {
  int tid = threadIdx.x;
  int head = tid & 7, hwi = tid >> 3;
  int bi = blockIdx.x;                          // 1152 = 9 * 4 * 32
  int tq = bi >> 7;
  int rest = bi & 127;
  int b = rest >> 5, hwg = rest & 31;
  int hw = (hwg << 5) + hwi;
  long base = (long)(b * TQ_) * 1024 + hw;
  const float scale = 0.17677669529663687f;

  float qf[32];
  long qoff = (base + (long)tq * 1024) * 768 + head * 32;
  #pragma unroll
  for (int i = 0; i < 4; ++i) {
    bf16x8 t = *(const bf16x8*)(qkv + qoff + i * 8);
    #pragma unroll
    for (int e = 0; e < 8; ++e) qf[i * 8 + e] = bs2f((ushort_t)t[e]);
  }
  float s[9];
  #pragma unroll
  for (int tk = 0; tk < 9; ++tk) {
    long ko = (base + (long)tk * 1024) * 768 + 256 + head * 32;
    float d = 0.f;
    #pragma unroll
    for (int i = 0; i < 4; ++i) {
      bf16x8 t = *(const bf16x8*)(qkv + ko + i * 8);
      #pragma unroll
      for (int e = 0; e < 8; ++e) d += qf[i * 8 + e] * bs2f((ushort_t)t[e]);
    }
    s[tk] = d * scale;
  }
  float mx = s[0];
  #pragma unroll
  for (int tk = 1; tk < 9; ++tk) mx = fmaxf(mx, s[tk]);
  float sum = 0.f;
  #pragma unroll
  for (int tk = 0; tk < 9; ++tk) { s[tk] = __expf(s[tk] - mx); sum += s[tk]; }
  float inv = 1.f / sum;

  float o[32];
  #pragma unroll
  for (int i = 0; i < 32; ++i) o[i] = 0.f;
  #pragma unroll
  for (int tk = 0; tk < 9; ++tk) {
    long vo = (base + (long)tk * 1024) * 768 + 512 + head * 32;
    #pragma unroll
    for (int i = 0; i < 4; ++i) {
      bf16x8 t = *(const bf16x8*)(qkv + vo + i * 8);
      #pragma unroll
      for (int e = 0; e < 8; ++e) o[i * 8 + e] += s[tk] * bs2f((ushort_t)t[e]);
    }
  }
  #pragma unroll
  for (int i = 0; i < 4; ++i) {
    bf16x8 t;
    #pragma unroll
    for (int e = 0; e < 8; ++e) t[e] = (short)f2bs(o[i * 8 + e] * inv);
    *(bf16x8*)(qkv + qoff + i * 8) = t;
  }
}

// copy query frame 8 into x (f32); identical linear indices in both buffers
__global__ __launch_bounds__(256)
void copy_frame8_kernel(const float* __restrict__ qy, float* __restrict__ x) {
  long i = (long)blockIdx.x * 256 + threadIdx.x;
  int b = (int)(i >> 18);
  long rem = i & ((1L << 18) - 1);
  long gi = ((long)(b * TQ_ + 8) << 18) + rem;
  x[gi] = qy[gi];
}

// CLS frame mean over spatial: partial sums then broadcast (on f32 x)
__global__ __launch_bounds__(256)
void cls_sum_kernel(const float* __restrict__ x, float* __restrict__ partial) {
  int b = blockIdx.x >> 5, ch = blockIdx.x & 31;
  int d = threadIdx.x;
  long base = ((long)(b * TQ_) * 1024 + ch * 32) * 256 + d;
  float s = 0.f;
  for (int r = 0; r < 32; ++r) s += x[base + (long)r * 256];
  partial[(long)blockIdx.x * 256 + d] = s;
}

__global__ __launch_bounds__(256)
void cls_bcast_kernel(float* __restrict__ x, const float* __restrict__ partial) {
  int b = blockIdx.x >> 3, seg = blockIdx.x & 7;
  int d = threadIdx.x;
  float s = 0.f;
  for (int j = 0; j < 32; ++j) s += partial[(long)(b * 32 + j) * 256 + d];
  s *= (1.f / 1024.f);
  long base = ((long)(b * TQ_) * 1024 + seg * 128) * 256 + d;
  for (int r = 0; r < 128; ++r) x[base + (long)r * 256] = s;
}

// ---------------------------------------------------------------------------
extern "C" void kernel_launch(void* const* d_in, const int* in_sizes, int n_in,
                              void* d_out, int out_size, void* d_ws, size_t ws_size,
                              hipStream_t stream) {
  (void)in_sizes; (void)n_in; (void)out_size; (void)ws_size;
  const float* query = (const float*)d_in[0];
  const float* sln_g = (const float*)d_in[3];
  const float* sln_b = (const float*)d_in[4];
  const float* s_wq  = (const float*)d_in[5];
  const float* s_bq  = (const float*)d_in[6];
  const float* s_wk  = (const float*)d_in[7];
  const float* s_bk  = (const float*)d_in[8];
  const float* s_wv  = (const float*)d_in[9];
  const float* s_bv  = (const float*)d_in[10];
  const float* s_wo  = (const float*)d_in[11];
  const float* s_bo  = (const float*)d_in[12];
  const float* tln_g = (const float*)d_in[13];
  const float* tln_b = (const float*)d_in[14];
  const float* t_wq  = (const float*)d_in[15];
  const float* t_bq  = (const float*)d_in[16];
  const float* t_wk  = (const float*)d_in[17];
  const float* t_bk  = (const float*)d_in[18];
  const float* t_wv  = (const float*)d_in[19];
  const float* t_bv  = (const float*)d_in[20];
  const float* t_wo  = (const float*)d_in[21];
  const float* t_bo  = (const float*)d_in[22];
  const float* mln_g = (const float*)d_in[23];
  const float* mln_b = (const float*)d_in[24];
  const float* w1    = (const float*)d_in[25];
  const float* b1    = (const float*)d_in[26];
  const float* w2    = (const float*)d_in[27];
  const float* b2    = (const float*)d_in[28];
  float* out = (float*)d_out;

  // ---- workspace ----
  const long RB = 36864L * 256;
  ushort_t* XA  = (ushort_t*)d_ws;          // RB bf16
  ushort_t* QKV = XA + RB;                  // 3*RB bf16, rows of 768
  float*    P4  = (float*)(QKV + 3 * RB);   // RB f32
  ushort_t* wt  = (ushort_t*)(P4 + RB);     // 2 MB packed weights
  float* bias2  = (float*)(wt + 1048576);   // 2x768 f32
  float* clsp   = bias2 + 1536;             // 128*256 f32

  ushort_t* pk_sqkv = wt;                   // packed [768][256]
  ushort_t* pk_tqkv = wt + 196608;          // packed [768][256]
  ushort_t* pk_swo  = wt + 393216;          // packed [256][256]
  ushort_t* pk_two  = wt + 458752;          // packed [256][256]
  ushort_t* pk_w1   = wt + 524288;          // packed [1024][256]
  ushort_t* pk_w2   = wt + 786432;          // packed [256][1024]

  // ---- weight / bias prep (one pack dispatch) ----
  TPA tp;
  tp.s[0] = s_wq; tp.d[0] = pk_sqkv;          tp.K[0] = 256;  tp.N[0] = 256;  tp.pm[0] = 1;
  tp.s[1] = s_wk; tp.d[1] = pk_sqkv + 65536;  tp.K[1] = 256;  tp.N[1] = 256;  tp.pm[1] = 1;
  tp.s[2] = s_wv; tp.d[2] = pk_sqkv + 131072; tp.K[2] = 256;  tp.N[2] = 256;  tp.pm[2] = 0;
  tp.s[3] = t_wq; tp.d[3] = pk_tqkv;          tp.K[3] = 256;  tp.N[3] = 256;  tp.pm[3] = 1;
  tp.s[4] = t_wk; tp.d[4] = pk_tqkv + 65536;  tp.K[4] = 256;  tp.N[4] = 256;  tp.pm[4] = 1;
  tp.s[5] = t_wv; tp.d[5] = pk_tqkv + 131072; tp.K[5] = 256;  tp.N[5] = 256;  tp.pm[5] = 0;
  tp.s[6] = s_wo; tp.d[6] = pk_swo;           tp.K[6] = 256;  tp.N[6] = 256;  tp.pm[6] = 0;
  tp.s[7] = t_wo; tp.d[7] = pk_two;           tp.K[7] = 256;  tp.N[7] = 256;  tp.pm[7] = 0;
  tp.s[8] = w1;   tp.d[8] = pk_w1;            tp.K[8] = 256;  tp.N[8] = 1024; tp.pm[8] = 0;
  tp.s[9] = w2;   tp.d[9] = pk_w2;            tp.K[9] = 1024; tp.N[9] = 256;  tp.pm[9] = 0;
  pack_all_kernel<<<dim3(32, 32, 10), 256, 0, stream>>>(tp);
  BC6 bc;
  bc.b[0] = s_bq; bc.b[1] = s_bk; bc.b[2] = s_bv;
  bc.b[3] = t_bq; bc.b[4] = t_bk; bc.b[5] = t_bv;
  bias_concat_kernel<<<2, 768, 0, stream>>>(bc, bias2);

  // grid = (M/128)*(N/64) blocks, XCD-group-swizzled inside; NBq = N/256
  #define WGEMM(KV, Ap, ldav, Wp, bi, rs, CF, CB, M, N, rm, om, ac, rp)     \
    wgemm_kernel<KV><<<dim3(((M) / 128) * ((N) / 64)), 256, 0, stream>>>(   \
        Ap, ldav, Wp, bi, rs, CF, CB, N, (N) / 256, rm, om, ac, rp)

  // ---- spatial windowed attention (frames 0..7), M=32768 ----
  ln_norm_kernel<<<8192, 256, 0, stream>>>(query, 1, sln_g, sln_b, XA);
  WGEMM(256, XA, 256, pk_sqkv, bias2, nullptr, nullptr, QKV,
        32768, 768, 0, 2, 0, 0);
  spatial_attn_kernel<<<1024, 256, 0, stream>>>(QKV);
  WGEMM(256, QKV, 768, pk_swo, s_bo, query, P4, nullptr,
        32768, 256, 2, 1, 0, 0);
  copy_frame8_kernel<<<4096, 256, 0, stream>>>(query, P4);

  // ---- temporal RoPE attention, M=36864 ----
  ln_norm_kernel<<<9216, 256, 0, stream>>>(P4, 0, tln_g, tln_b, XA);
  WGEMM(256, XA, 256, pk_tqkv, bias2 + 768, nullptr, nullptr, QKV,
        36864, 768, 0, 2, 0, 1);
  temporal_attn_kernel<<<1152, 256, 0, stream>>>(QKV);
  WGEMM(256, QKV, 768, pk_two, t_bo, P4, out, nullptr,
        36864, 256, 1, 0, 0, 0);

  // ---- CLS frame spatial mean + broadcast (on out = x2) ----
  cls_sum_kernel<<<128, 256, 0, stream>>>(out, clsp);
  cls_bcast_kernel<<<32, 256, 0, stream>>>(out, clsp);

  // ---- FUSED MLP v3 (ln + w1 + gelu + w2 + resid), in place on out ----
  mlp_fused_kernel<<<576, 256, 0, stream>>>(out, pk_w1, b1, pk_w2, b2,
                                            mln_g, mln_b);
  #undef WGEMM
}

// Round 10
// 492.876 us; speedup vs baseline: 1.9961x; 1.0247x over previous
//
#include <hip/hip_runtime.h>
#include <math.h>

#define TQ_  9

typedef unsigned int   u32;
typedef unsigned short ushort_t;
typedef short bf16x8 __attribute__((ext_vector_type(8)));
typedef float f32x4  __attribute__((ext_vector_type(4)));

__device__ __forceinline__ float bs2f(ushort_t s) {
  return __uint_as_float(((u32)s) << 16);
}
__device__ __forceinline__ ushort_t f2bs(float x) {   // round-to-nearest-even
  u32 u = __float_as_uint(x);
  u32 r = (u + 0x7FFFu + ((u >> 16) & 1u)) >> 16;
  return (ushort_t)r;
}

// fast gelu: 0.5x(1+erf(x/sqrt2)), erf via Abramowitz-Stegun 7.1.26
// (|abs err| < 1.5e-7, far below bf16 rounding). ~15 VALU ops vs erff's ~30+.
__device__ __forceinline__ float gelu_f(float x) {
  float z = x * 0.70710678118654752f;
  float a = fabsf(z);
  float t = __builtin_amdgcn_rcpf(1.f + 0.3275911f * a);
  float poly = t * (0.254829592f + t * (-0.284496736f +
               t * (1.421413741f + t * (-1.453152027f + t * 1.061405429f))));
  float erfv = 1.f - poly * __expf(-z * z);
  erfv = (z < 0.f) ? -erfv : erfv;
  return 0.5f * x * (1.f + erfv);
}

// ---------------------------------------------------------------------------
// Weight PACK: W f32 [K][N] -> MFMA-frag-linear bf16 (A-operand layout).
// Frag group G = (j*(K/32) + kk)*64 + q*16 + ln holds 8 bf16:
//   element e: out-col n = j*16+ln, k = kk*32 + q*8 + e.
// pm=1 (Q/K weights): out-columns permuted within each 32-col head so RoPE
// pairs (d, d+16) sit at positions c, c^8 of a 16-col chunk.
// ---------------------------------------------------------------------------
struct TPA { const float* s[10]; ushort_t* d[10]; int K[10]; int N[10]; int pm[10]; };

__global__ __launch_bounds__(256)
void pack_all_kernel(TPA p) {
  int z = blockIdx.z;
  int K = p.K[z], N = p.N[z];
  int bn = blockIdx.x << 5, bk = blockIdx.y << 5;
  if (bn >= N || bk >= K) return;
  const float* W = p.s[z];
  ushort_t* pk = p.d[z];
  int pm = p.pm[z];
  __shared__ float t[32][33];                 // [k_local][n_local]
  int tid = threadIdx.x;
  int tx = tid & 31, ty = tid >> 5;
  #pragma unroll
  for (int r = 0; r < 4; ++r)
    t[ty + (r << 3)][tx] = W[(long)(bk + ty + (r << 3)) * N + bn + tx];
  __syncthreads();
  if (tid < 128) {
    int jl = tid >> 6, q = (tid >> 4) & 3, ln = tid & 15;
    int j = (bn >> 4) + jl, kk = bk >> 5;
    int colsrc = pm ? ((ln & 7) + (jl << 3) + ((ln & 8) << 1))
                    : ((jl << 4) + ln);
    long G = (((long)j * (K >> 5) + kk) << 6) + (q << 4) + ln;
    bf16x8 ov;
    #pragma unroll
    for (int e = 0; e < 8; ++e)
      ov[e] = (short)f2bs(t[(q << 3) + e][colsrc]);
    *(bf16x8*)(pk + (G << 3)) = ov;
  }
}

// concat 3 biases x 2 stages into f32 [2][768]; Q/K parts permuted to match
struct BC6 { const float* b[6]; };
__global__ __launch_bounds__(768)
void bias_concat_kernel(BC6 p, float* __restrict__ dst) {
  int z = blockIdx.x, n = threadIdx.x;
  int w = n >> 8, q = n & 255;
  int psrc = q;
  if (w < 2)
    psrc = (q & 0xE0) | (q & 7) | (((q >> 4) & 1) << 3) | (((q >> 3) & 1) << 4);
  dst[z * 768 + n] = p.b[z * 3 + w][psrc];
}

// ---------------------------------------------------------------------------
// LayerNorm materialize: one wave per row (4 rows/block), float4 loads.
// ---------------------------------------------------------------------------
__global__ __launch_bounds__(256)
void ln_norm_kernel(const float* __restrict__ src, int spatial,
                    const float* __restrict__ g, const float* __restrict__ b,
                    ushort_t* __restrict__ dst) {
  int row = blockIdx.x * 4 + (threadIdx.x >> 6);
  int lane = threadIdx.x & 63;
  long srow = row;
  if (spatial) {
    int bq = row >> 13, r = row & 8191;
    srow = ((long)(bq * TQ_ + (r >> 10)) << 10) + (r & 1023);
  }
  float4 v = ((const float4*)(src + srow * 256))[lane];
  float s  = v.x + v.y + v.z + v.w;
  float s2 = v.x * v.x + v.y * v.y + v.z * v.z + v.w * v.w;
  #pragma unroll
  for (int m = 32; m; m >>= 1) {
    s  += __shfl_xor(s,  m, 64);
    s2 += __shfl_xor(s2, m, 64);
  }
  float mean = s * (1.f / 256.f);
  float rstd = rsqrtf(s2 * (1.f / 256.f) - mean * mean + 1e-5f);
  float4 gv = ((const float4*)g)[lane];
  float4 bv = ((const float4*)b)[lane];
  ushort_t o[4];
  o[0] = f2bs((v.x - mean) * rstd * gv.x + bv.x);
  o[1] = f2bs((v.y - mean) * rstd * gv.y + bv.y);
  o[2] = f2bs((v.z - mean) * rstd * gv.z + bv.z);
  o[3] = f2bs((v.w - mean) * rstd * gv.w + bv.w);
  u32 lo = (u32)o[0] | ((u32)o[1] << 16);
  u32 hi = (u32)o[2] | ((u32)o[3] << 16);
  uint2 pk; pk.x = lo; pk.y = hi;
  *(uint2*)(dst + (long)row * 256 + lane * 4) = pk;
}

// ---------------------------------------------------------------------------
// Barrier-free register-streaming GEMM (no LDS), swapped operand order:
//   D = W_frag (A-op, n-rows) x X_frag (B-op, m-cols) -> lane-contiguous cols.
// (unchanged from round 5 — verified, handles the 4 attn-stage GEMMs)
// ---------------------------------------------------------------------------
template<int K>
__global__ __launch_bounds__(256, 4)
void wgemm_kernel(const ushort_t* __restrict__ A, int lda,
                  const ushort_t* __restrict__ packW,
                  const float* __restrict__ bias, const float* __restrict__ resid,
                  float* __restrict__ Cf, ushort_t* __restrict__ Cb,
                  int N, int NBq, int resid_mode, int out_mode, int act, int rope) {
  constexpr int K32 = K / 32;
  constexpr int AD = (K32 >= 4) ? 4 : K32;    // X prefetch depth (reg ring)
  constexpr int BD = 2;                       // W prefetch depth

  int tid = threadIdx.x;
  int wv = tid >> 6, lane = tid & 63;
  int ln = lane & 15, q4 = lane >> 4;

  // XCD-grouping decode
  int gid = blockIdx.x;
  int g = gid >> 5, r = gid & 31;
  int nq = (r >> 3) + ((g % NBq) << 2);
  int mb = ((g / NBq) << 3) + (r & 7);
  int m0 = mb << 7, n0 = nq << 6;

  const ushort_t* Ap = A + (long)(m0 + (wv << 5) + ln) * lda + (q4 << 3);
  long a16 = (long)lda << 4;                  // +16 rows
  const ushort_t* Bp = packW + (((long)(nq << 2) * K32) << 9) + (lane << 3);

  bf16x8 xr[AD][2];                           // X fragments (B-operand)
  bf16x8 wr[BD][4];                           // W fragments (A-operand)
  #pragma unroll
  for (int d = 0; d < BD; ++d)
    #pragma unroll
    for (int j = 0; j < 4; ++j)
      wr[d][j] = *(const bf16x8*)(Bp + (((long)j * K32 + d) << 9));
  #pragma unroll
  for (int d = 0; d < AD; ++d) {
    xr[d][0] = *(const bf16x8*)(Ap + d * 32);
    xr[d][1] = *(const bf16x8*)(Ap + a16 + d * 32);
  }

  f32x4 acc[2][4];
  #pragma unroll
  for (int i = 0; i < 2; ++i)
    #pragma unroll
    for (int j = 0; j < 4; ++j) acc[i][j] = 0.f;

  #pragma unroll
  for (int kk = 0; kk < K32; ++kk) {          // fully unrolled: static indices
    #pragma unroll
    for (int i = 0; i < 2; ++i)
      #pragma unroll
      for (int j = 0; j < 4; ++j)
        acc[i][j] = __builtin_amdgcn_mfma_f32_16x16x32_bf16(
            wr[kk % BD][j], xr[kk % AD][i], acc[i][j], 0, 0, 0);
    if (kk + AD < K32) {
      xr[kk % AD][0] = *(const bf16x8*)(Ap + (kk + AD) * 32);
      xr[kk % AD][1] = *(const bf16x8*)(Ap + a16 + (kk + AD) * 32);
    }
    if (kk + BD < K32) {
      #pragma unroll
      for (int j = 0; j < 4; ++j)
        wr[kk % BD][j] = *(const bf16x8*)(Bp + (((long)j * K32 + kk + BD) << 9));
    }
    __builtin_amdgcn_sched_barrier(0);        // pin prefetch distance
  }

  // ---- epilogue (all lane-contiguous: float4 / uint2) ----
  float4 bj[4];
  #pragma unroll
  for (int j = 0; j < 4; ++j)
    bj[j] = *(const float4*)(bias + n0 + (j << 4) + (q4 << 2));

  float cs_c[2][4], cs_s[2][4];
  if (rope) {
    int t = (m0 >> 10) % TQ_;
    #pragma unroll
    for (int p = 0; p < 2; ++p)
      #pragma unroll
      for (int r2 = 0; r2 < 4; ++r2) {
        float d = (float)(((q4 & 1) << 2) + r2 + (p << 3));
        float ang = (float)t * exp2f(d * -0.8304820237218406f);
        cs_c[p][r2] = cosf(ang);
        float s = sinf(ang);
        cs_s[p][r2] = (q4 & 2) ? s : -s;      // x1 lanes: -s, x2 lanes: +s
      }
  }

  #pragma unroll
  for (int i = 0; i < 2; ++i) {
    int m = m0 + (wv << 5) + (i << 4) + ln;   // per-lane output row
    long orow = m;
    if (out_mode == 1 || resid_mode == 2) {
      int bq = m >> 13, rr = m & 8191;
      orow = ((long)(bq * TQ_ + (rr >> 10)) << 10) + (rr & 1023);
    }
    #pragma unroll
    for (int j = 0; j < 4; ++j) {
      int n = n0 + (j << 4) + (q4 << 2);      // 4 consecutive cols per lane
      float v[4];
      #pragma unroll
      for (int r2 = 0; r2 < 4; ++r2) v[r2] = acc[i][j][r2] + bj[j][r2];
      if (rope && ((nq << 2) + j) < 32) {     // Q,K region (first 512 cols)
        #pragma unroll
        for (int r2 = 0; r2 < 4; ++r2) {
          float other = __shfl_xor(v[r2], 32, 64);
          v[r2] = v[r2] * cs_c[j & 1][r2] + other * cs_s[j & 1][r2];
        }
      }
      if (act) {
        #pragma unroll
        for (int r2 = 0; r2 < 4; ++r2) v[r2] = gelu_f(v[r2]);
      }
      if (resid_mode == 1) {
        float4 rv = *(const float4*)(resid + (long)m * 256 + n);
        v[0] += rv.x; v[1] += rv.y; v[2] += rv.z; v[3] += rv.w;
      } else if (resid_mode == 2) {
        float4 rv = *(const float4*)(resid + orow * 256 + n);
        v[0] += rv.x; v[1] += rv.y; v[2] += rv.z; v[3] += rv.w;
      }
      if (out_mode == 2) {
        uint2 pk;
        pk.x = (u32)f2bs(v[0]) | ((u32)f2bs(v[1]) << 16);
        pk.y = (u32)f2bs(v[2]) | ((u32)f2bs(v[3]) << 16);
        *(uint2*)(Cb + (long)m * N + n) = pk;
      } else {
        float4 o4; o4.x = v[0]; o4.y = v[1]; o4.z = v[2]; o4.w = v[3];
        if (out_mode == 1) *(float4*)(Cf + orow * 256 + n) = o4;
        else               *(float4*)(Cf + (long)m * N + n) = o4;
      }
    }
  }
}

// ---------------------------------------------------------------------------
// FUSED MLP v4: out = x + (gelu(LN(x) @ W1 + b1) @ W2 + b2), in place.
// ROUND-9 LESSON: v3's halved weight traffic bought only 5% -> kernel is
// dependency-latency-bound at 2 waves/SIMD, not traffic-bound. v4 maximizes
// RESIDENCY: 32 rows/block (1152 blocks = 4.5 blocks/CU of work), hid in
// quarters so LDS = 16 KB XL + 16 KB HLDS = 32 KB -> 4-5 blocks/CU resident
// (16-20 waves/CU, 2-2.5x v3). VGPR capped at 128 via launch_bounds(256,4).
// Weight L2 traffic returns to 1.15 GB but overlaps across 4+ blocks/CU.
// Keeps: fast A&S gelu, 2-deep register weight prefetch + sched_barrier(0).
// Phases: LN -> sync -> 4x { w1(64-col chunk/wave)+gelu->HLDS -> sync ->
// w2 partial acc -> sync } -> epilogue (+b2 +x, float4, in place).
// ---------------------------------------------------------------------------
__device__ __forceinline__ int tl_off(int row, int col) {   // 256-col bf16 tile
  return (row << 8) + (((((col >> 3) + row) & 31)) << 3) + (col & 7);
}

__global__ __launch_bounds__(256, 4)
void mlp_fused_kernel(float* xio,                       // in/out (same buffer)
                      const ushort_t* __restrict__ W1p, // packed [1024][256]
                      const float* __restrict__ b1,
                      const ushort_t* __restrict__ W2p, // packed [256][1024]
                      const float* __restrict__ b2,
                      const float* __restrict__ g,
                      const float* __restrict__ be) {
  __shared__ ushort_t XL[8192];     // 16 KB: 32x256 normalized X (swizzled)
  __shared__ ushort_t HLDS[8192];   // 16 KB: 32x256 hid quarter (swizzled)
  int tid = threadIdx.x;
  int wv = tid >> 6, lane = tid & 63;
  int ln = lane & 15, q4 = lane >> 4;
  int m0 = blockIdx.x << 5;                   // 32 rows

  // ---- LN: wave wv rows wv*8..+7; 8 lanes/row (shfl_xor 1,2,4) ----
  {
    int lrow = (wv << 3) + (lane >> 3);       // local row 0..31
    int p = lane & 7;
    const float* xr = xio + (long)(m0 + lrow) * 256 + (p << 2);
    float s = 0.f, s2 = 0.f;
    float4 vbuf[8];
    #pragma unroll
    for (int k = 0; k < 8; ++k) {
      float4 a = *(const float4*)(xr + (k << 5));
      vbuf[k] = a;
      s  += a.x + a.y + a.z + a.w;
      s2 += a.x*a.x + a.y*a.y + a.z*a.z + a.w*a.w;
    }
    s  += __shfl_xor(s,  1, 64);  s  += __shfl_xor(s,  2, 64);  s  += __shfl_xor(s,  4, 64);
    s2 += __shfl_xor(s2, 1, 64);  s2 += __shfl_xor(s2, 2, 64);  s2 += __shfl_xor(s2, 4, 64);
    float mean = s * (1.f / 256.f);
    float rstd = rsqrtf(s2 * (1.f / 256.f) - mean * mean + 1e-5f);
    #pragma unroll
    for (int k = 0; k < 8; ++k) {
      int col = (p << 2) + (k << 5);
      float4 gv = *(const float4*)(g + col);
      float4 bv = *(const float4*)(be + col);
      float4 a = vbuf[k];
      u32 lo = (u32)f2bs((a.x - mean) * rstd * gv.x + bv.x)
             | ((u32)f2bs((a.y - mean) * rstd * gv.y + bv.y) << 16);
      u32 hi = (u32)f2bs((a.z - mean) * rstd * gv.z + bv.z)
             | ((u32)f2bs((a.w - mean) * rstd * gv.w + bv.w) << 16);
      uint2 pk; pk.x = lo; pk.y = hi;
      *(uint2*)&XL[tl_off(lrow, col)] = pk;
    }
  }
  __syncthreads();

  f32x4 acc[2][4];                            // out acc: 2 i x 4 jl (32 VGPR)
  #pragma unroll
  for (int i = 0; i < 2; ++i)
    #pragma unroll
    for (int jl = 0; jl < 4; ++jl) acc[i][jl] = 0.f;

  #pragma unroll 1
  for (int q = 0; q < 4; ++q) {               // hid quarters of 256 cols
    // ---- w1: wave wv -> global 64-col chunk c = q*4+wv ----
    {
      int c = (q << 2) + wv;
      f32x4 h[2][4];
      #pragma unroll
      for (int i = 0; i < 2; ++i)
        #pragma unroll
        for (int jj = 0; jj < 4; ++jj) h[i][jj] = 0.f;

      bf16x8 wf[2][4];
      #pragma unroll
      for (int jj = 0; jj < 4; ++jj)
        wf[0][jj] = *(const bf16x8*)(W1p + (((long)((c << 2) + jj) * 8) << 9) + (lane << 3));
      #pragma unroll
      for (int ks = 0; ks < 8; ++ks) {
        if (ks + 1 < 8) {                     // prefetch next (no WAR: other buf)
          #pragma unroll
          for (int jj = 0; jj < 4; ++jj)
            wf[(ks + 1) & 1][jj] = *(const bf16x8*)(W1p +
                (((long)((c << 2) + jj) * 8 + ks + 1) << 9) + (lane << 3));
        }
        int col = (q4 << 3) + (ks << 5);
        bf16x8 xf0 = *(const bf16x8*)&XL[tl_off(ln, col)];
        bf16x8 xf1 = *(const bf16x8*)&XL[tl_off(16 + ln, col)];
        #pragma unroll
        for (int jj = 0; jj < 4; ++jj) {
          h[0][jj] = __builtin_amdgcn_mfma_f32_16x16x32_bf16(
              wf[ks & 1][jj], xf0, h[0][jj], 0, 0, 0);
          h[1][jj] = __builtin_amdgcn_mfma_f32_16x16x32_bf16(
              wf[ks & 1][jj], xf1, h[1][jj], 0, 0, 0);
        }
        __builtin_amdgcn_sched_barrier(0);
      }
      // +b1, fast gelu, pack -> HLDS (local col = wv*64 + jj*16 + q4*4)
      #pragma unroll
      for (int jj = 0; jj < 4; ++jj) {
        float4 b1v = *(const float4*)(b1 + (c << 6) + (jj << 4) + (q4 << 2));
        #pragma unroll
        for (int i = 0; i < 2; ++i) {
          float v[4];
          v[0] = gelu_f(h[i][jj][0] + b1v.x);
          v[1] = gelu_f(h[i][jj][1] + b1v.y);
          v[2] = gelu_f(h[i][jj][2] + b1v.z);
          v[3] = gelu_f(h[i][jj][3] + b1v.w);
          uint2 pk;
          pk.x = (u32)f2bs(v[0]) | ((u32)f2bs(v[1]) << 16);
          pk.y = (u32)f2bs(v[2]) | ((u32)f2bs(v[3]) << 16);
          *(uint2*)&HLDS[tl_off((i << 4) + ln, (wv << 6) + (jj << 4) + (q4 << 2))] = pk;
        }
      }
    }
    __syncthreads();

    // ---- w2 partial: wave wv -> out cols wv*64..+63; k = quarter cols ----
    {
      bf16x8 wf2[2][4];
      #pragma unroll
      for (int jl = 0; jl < 4; ++jl)
        wf2[0][jl] = *(const bf16x8*)(W2p +
            (((long)((wv << 2) + jl) * 32 + (q << 3)) << 9) + (lane << 3));
      #pragma unroll
      for (int kc = 0; kc < 8; ++kc) {
        if (kc + 1 < 8) {
          #pragma unroll
          for (int jl = 0; jl < 4; ++jl)
            wf2[(kc + 1) & 1][jl] = *(const bf16x8*)(W2p +
                (((long)((wv << 2) + jl) * 32 + (q << 3) + kc + 1) << 9) + (lane << 3));
        }
        int col = (kc << 5) + (q4 << 3);
        bf16x8 hb0 = *(const bf16x8*)&HLDS[tl_off(ln, col)];
        bf16x8 hb1 = *(const bf16x8*)&HLDS[tl_off(16 + ln, col)];
        #pragma unroll
        for (int jl = 0; jl < 4; ++jl) {
          acc[0][jl] = __builtin_amdgcn_mfma_f32_16x16x32_bf16(
              wf2[kc & 1][jl], hb0, acc[0][jl], 0, 0, 0);
          acc[1][jl] = __builtin_amdgcn_mfma_f32_16x16x32_bf16(
              wf2[kc & 1][jl], hb1, acc[1][jl], 0, 0, 0);
        }
        __builtin_amdgcn_sched_barrier(0);
      }
    }
    __syncthreads();                          // before next quarter overwrites HLDS
  }

  // ---- epilogue: +b2 +resid(x), float4 stores, in place ----
  #pragma unroll
  for (int i = 0; i < 2; ++i) {
    long ro = (long)(m0 + (i << 4) + ln) * 256;
    #pragma unroll
    for (int jl = 0; jl < 4; ++jl) {
      int n = ((wv << 2) + jl) * 16 + (q4 << 2);
      float4 rv = *(const float4*)(xio + ro + n);
      float4 bv = *(const float4*)(b2 + n);
      float4 o;
      o.x = acc[i][jl][0] + bv.x + rv.x;
      o.y = acc[i][jl][1] + bv.y + rv.y;
      o.z = acc[i][jl][2] + bv.z + rv.z;
      o.w = acc[i][jl][3] + bv.w + rv.w;
      *(float4*)(xio + ro + n) = o;
    }
  }
}

// ---------------------------------------------------------------------------
// Spatial 3x3 windowed attention on packed QKV [m][768] bf16.
// ---------------------------------------------------------------------------
__global__ __launch_bounds__(256)
void spatial_attn_kernel(ushort_t* __restrict__ qkv) {
  int gid = blockIdx.x * 256 + threadIdx.x;   // 262144
  int head = gid & 7, pixel = gid >> 3;
  int pix = pixel & 1023, bt = pixel >> 10;
  int y = pix >> 5, x = pix & 31;
  long rb = (long)bt << 10;
  const float scale = 0.17677669529663687f;   // 1/sqrt(32)

  float qf[32];
  long qoff = (long)pixel * 768 + head * 32;
  #pragma unroll
  for (int i = 0; i < 4; ++i) {
    bf16x8 t = *(const bf16x8*)(qkv + qoff + i * 8);
    #pragma unroll
    for (int e = 0; e < 8; ++e) qf[i * 8 + e] = bs2f((ushort_t)t[e]);
  }

  float s[9];
  bool val[9];
  #pragma unroll
  for (int n = 0; n < 9; ++n) {
    int yy = y + n / 3 - 1, xx = x + n % 3 - 1;
    bool ok = ((unsigned)yy < 32u) & ((unsigned)xx < 32u);
    val[n] = ok;
    float d = 0.f;
    if (ok) {
      long ko = (rb + (yy << 5) + xx) * 768 + 256 + head * 32;
      #pragma unroll
      for (int i = 0; i < 4; ++i) {
        bf16x8 t = *(const bf16x8*)(qkv + ko + i * 8);
        #pragma unroll
        for (int e = 0; e < 8; ++e) d += qf[i * 8 + e] * bs2f((ushort_t)t[e]);
      }
    }
    s[n] = d * scale;
  }
  float mx = -1e30f;
  #pragma unroll
  for (int n = 0; n < 9; ++n) if (val[n]) mx = fmaxf(mx, s[n]);
  float sum = 0.f;
  #pragma unroll
  for (int n = 0; n < 9; ++n) { s[n] = val[n] ? __expf(s[n] - mx) : 0.f; sum += s[n]; }
  float inv = 1.f / sum;

  float o[32];
  #pragma unroll
  for (int i = 0; i < 32; ++i) o[i] = 0.f;
  #pragma unroll
  for (int n = 0; n < 9; ++n) {
    if (val[n]) {
      int yy = y + n / 3 - 1, xx = x + n % 3 - 1;
      long vo = (rb + (yy << 5) + xx) * 768 + 512 + head * 32;
      #pragma unroll
      for (int i = 0; i < 4; ++i) {
        bf16x8 t = *(const bf16x8*)(qkv + vo + i * 8);
        #pragma unroll
        for (int e = 0; e < 8; ++e) o[i * 8 + e] += s[n] * bs2f((ushort_t)t[e]);
      }
    }
  }
  #pragma unroll
  for (int i = 0; i < 4; ++i) {
    bf16x8 t;
    #pragma unroll
    for (int e = 0; e < 8; ++e) t[e] = (short)f2bs(o[i * 8 + e] * inv);
    *(bf16x8*)(qkv + qoff + i * 8) = t;
  }
}

// ---------------------------------------------------------------------------
// Temporal attention (full 9x9; mask all-False). o over q in-place.
// ---------------------------------------------------------------------------
__global__ __launch_bounds__(256)
void temporal_attn_kernel(ushort_t* __restrict__ qkv) {
  int tid = threadIdx.x;
  int head = tid & 7, hwi = tid >> 3;
  int bi = blockIdx.x;                          // 1152 = 9 * 4 * 32
  int tq = bi >> 7;
  int rest = bi & 127;
  int b = rest >> 5, hwg = rest & 31;
  int hw = (hwg << 5) + hwi;
  long base = (long)(b * TQ_) * 1024 + hw;
  const float scale = 0.17677669529663687f;

  float qf[32];
  long qoff = (base + (long)tq * 1024) * 768 + head * 32;
  #pragma unroll
  for (int i = 0; i < 4; ++i) {
    bf16x8 t = *(const bf16x8*)(qkv + qoff + i * 8);
    #pragma unroll
    for (int e = 0; e < 8; ++e) qf[i * 8 + e] = bs2f((ushort_t)t[e]);
  }
  float s[9];
  #pragma unroll
  for (int tk = 0; tk < 9; ++tk) {
    long ko = (base + (long)tk * 1024) * 768 + 256 + head * 32;
    float d = 0.f;
    #pragma unroll
    for (int i = 0; i < 4; ++i) {
      bf16x8 t = *(const bf16x8*)(qkv + ko + i * 8);
      #pragma unroll
      for (int e = 0; e < 8; ++e) d += qf[i * 8 + e] * bs2f((ushort_t)t[e]);
    }
    s[tk] = d * scale;
  }
  float mx = s[0];
  #pragma unroll
  for (int tk = 1; tk < 9; ++tk) mx = fmaxf(mx, s[tk]);
  float sum = 0.f;
  #pragma unroll
  for (int tk = 0; tk < 9; ++tk) { s[tk] = __expf(s[tk] - mx); sum += s[tk]; }
  float inv = 1.f / sum;

  float o[32];
  #pragma unroll
  for (int i = 0; i < 32; ++i) o[i] = 0.f;
  #pragma unroll
  for (int tk = 0; tk < 9; ++tk) {
    long vo = (base + (long)tk * 1024) * 768 + 512 + head * 32;
    #pragma unroll
    for (int i = 0; i < 4; ++i) {
      bf16x8 t = *(const bf16x8*)(qkv + vo + i * 8);
      #pragma unroll
      for (int e = 0; e < 8; ++e) o[i * 8 + e] += s[tk] * bs2f((ushort_t)t[e]);
    }
  }
  #pragma unroll
  for (int i = 0; i < 4; ++i) {
    bf16x8 t;
    #pragma unroll
    for (int e = 0; e < 8; ++e) t[e] = (short)f2bs(o[i * 8 + e] * inv);
    *(bf16x8*)(qkv + qoff + i * 8) = t;
  }
}

// copy query frame 8 into x (f32); identical linear indices in both buffers
__global__ __launch_bounds__(256)
void copy_frame8_kernel(const float* __restrict__ qy, float* __restrict__ x) {
  long i = (long)blockIdx.x * 256 + threadIdx.x;
  int b = (int)(i >> 18);
  long rem = i & ((1L << 18) - 1);
  long gi = ((long)(b * TQ_ + 8) << 18) + rem;
  x[gi] = qy[gi];
}

// CLS frame mean over spatial: partial sums then broadcast (on f32 x)
__global__ __launch_bounds__(256)
void cls_sum_kernel(const float* __restrict__ x, float* __restrict__ partial) {
  int b = blockIdx.x >> 5, ch = blockIdx.x & 31;
  int d = threadIdx.x;
  long base = ((long)(b * TQ_) * 1024 + ch * 32) * 256 + d;
  float s = 0.f;
  for (int r = 0; r < 32; ++r) s += x[base + (long)r * 256];
  partial[(long)blockIdx.x * 256 + d] = s;
}

__global__ __launch_bounds__(256)
void cls_bcast_kernel(float* __restrict__ x, const float* __restrict__ partial) {
  int b = blockIdx.x >> 3, seg = blockIdx.x & 7;
  int d = threadIdx.x;
  float s = 0.f;
  for (int j = 0; j < 32; ++j) s += partial[(long)(b * 32 + j) * 256 + d];
  s *= (1.f / 1024.f);
  long base = ((long)(b * TQ_) * 1024 + seg * 128) * 256 + d;
  for (int r = 0; r < 128; ++r) x[base + (long)r * 256] = s;
}

// ---------------------------------------------------------------------------
extern "C" void kernel_launch(void* const* d_in, const int* in_sizes, int n_in,
                              void* d_out, int out_size, void* d_ws, size_t ws_size,
                              hipStream_t stream) {
  (void)in_sizes; (void)n_in; (void)out_size; (void)ws_size;
  const float* query = (const float*)d_in[0];
  const float* sln_g = (const float*)d_in[3];
  const float* sln_b = (const float*)d_in[4];
  const float* s_wq  = (const float*)d_in[5];
  const float* s_bq  = (const float*)d_in[6];
  const float* s_wk  = (const float*)d_in[7];
  const float* s_bk  = (const float*)d_in[8];
  const float* s_wv  = (const float*)d_in[9];
  const float* s_bv  = (const float*)d_in[10];
  const float* s_wo  = (const float*)d_in[11];
  const float* s_bo  = (const float*)d_in[12];
  const float* tln_g = (const float*)d_in[13];
  const float* tln_b = (const float*)d_in[14];
  const float* t_wq  = (const float*)d_in[15];
  const float* t_bq  = (const float*)d_in[16];
  const float* t_wk  = (const float*)d_in[17];
  const float* t_bk  = (const float*)d_in[18];
  const float* t_wv  = (const float*)d_in[19];
  const float* t_bv  = (const float*)d_in[20];
  const float* t_wo  = (const float*)d_in[21];
  const float* t_bo  = (const float*)d_in[22];
  const float* mln_g = (const float*)d_in[23];
  const float* mln_b = (const float*)d_in[24];
  const float* w1    = (const float*)d_in[25];
  const float* b1    = (const float*)d_in[26];
  const float* w2    = (const float*)d_in[27];
  const float* b2    = (const float*)d_in[28];
  float* out = (float*)d_out;

  // ---- workspace ----
  const long RB = 36864L * 256;
  ushort_t* XA  = (ushort_t*)d_ws;          // RB bf16
  ushort_t* QKV = XA + RB;                  // 3*RB bf16, rows of 768
  float*    P4  = (float*)(QKV + 3 * RB);   // RB f32
  ushort_t* wt  = (ushort_t*)(P4 + RB);     // 2 MB packed weights
  float* bias2  = (float*)(wt + 1048576);   // 2x768 f32
  float* clsp   = bias2 + 1536;             // 128*256 f32

  ushort_t* pk_sqkv = wt;                   // packed [768][256]
  ushort_t* pk_tqkv = wt + 196608;          // packed [768][256]
  ushort_t* pk_swo  = wt + 393216;          // packed [256][256]
  ushort_t* pk_two  = wt + 458752;          // packed [256][256]
  ushort_t* pk_w1   = wt + 524288;          // packed [1024][256]
  ushort_t* pk_w2   = wt + 786432;          // packed [256][1024]

  // ---- weight / bias prep (one pack dispatch) ----
  TPA tp;
  tp.s[0] = s_wq; tp.d[0] = pk_sqkv;          tp.K[0] = 256;  tp.N[0] = 256;  tp.pm[0] = 1;
  tp.s[1] = s_wk; tp.d[1] = pk_sqkv + 65536;  tp.K[1] = 256;  tp.N[1] = 256;  tp.pm[1] = 1;
  tp.s[2] = s_wv; tp.d[2] = pk_sqkv + 131072; tp.K[2] = 256;  tp.N[2] = 256;  tp.pm[2] = 0;
  tp.s[3] = t_wq; tp.d[3] = pk_tqkv;          tp.K[3] = 256;  tp.N[3] = 256;  tp.pm[3] = 1;
  tp.s[4] = t_wk; tp.d[4] = pk_tqkv + 65536;  tp.K[4] = 256;  tp.N[4] = 256;  tp.pm[4] = 1;
  tp.s[5] = t_wv; tp.d[5] = pk_tqkv + 131072; tp.K[5] = 256;  tp.N[5] = 256;  tp.pm[5] = 0;
  tp.s[6] = s_wo; tp.d[6] = pk_swo;           tp.K[6] = 256;  tp.N[6] = 256;  tp.pm[6] = 0;
  tp.s[7] = t_wo; tp.d[7] = pk_two;           tp.K[7] = 256;  tp.N[7] = 256;  tp.pm[7] = 0;
  tp.s[8] = w1;   tp.d[8] = pk_w1;            tp.K[8] = 256;  tp.N[8] = 1024; tp.pm[8] = 0;
  tp.s[9] = w2;   tp.d[9] = pk_w2;            tp.K[9] = 1024; tp.N[9] = 256;  tp.pm[9] = 0;
  pack_all_kernel<<<dim3(32, 32, 10), 256, 0, stream>>>(tp);
  BC6 bc;
  bc.b[0] = s_bq; bc.b[1] = s_bk; bc.b[2] = s_bv;
  bc.b[3] = t_bq; bc.b[4] = t_bk; bc.b[5] = t_bv;
  bias_concat_kernel<<<2, 768, 0, stream>>>(bc, bias2);

  // grid = (M/128)*(N/64) blocks, XCD-group-swizzled inside; NBq = N/256
  #define WGEMM(KV, Ap, ldav, Wp, bi, rs, CF, CB, M, N, rm, om, ac, rp)     \
    wgemm_kernel<KV><<<dim3(((M) / 128) * ((N) / 64)), 256, 0, stream>>>(   \
        Ap, ldav, Wp, bi, rs, CF, CB, N, (N) / 256, rm, om, ac, rp)

  // ---- spatial windowed attention (frames 0..7), M=32768 ----
  ln_norm_kernel<<<8192, 256, 0, stream>>>(query, 1, sln_g, sln_b, XA);
  WGEMM(256, XA, 256, pk_sqkv, bias2, nullptr, nullptr, QKV,
        32768, 768, 0, 2, 0, 0);
  spatial_attn_kernel<<<1024, 256, 0, stream>>>(QKV);
  WGEMM(256, QKV, 768, pk_swo, s_bo, query, P4, nullptr,
        32768, 256, 2, 1, 0, 0);
  copy_frame8_kernel<<<4096, 256, 0, stream>>>(query, P4);

  // ---- temporal RoPE attention, M=36864 ----
  ln_norm_kernel<<<9216, 256, 0, stream>>>(P4, 0, tln_g, tln_b, XA);
  WGEMM(256, XA, 256, pk_tqkv, bias2 + 768, nullptr, nullptr, QKV,
        36864, 768, 0, 2, 0, 1);
  temporal_attn_kernel<<<1152, 256, 0, stream>>>(QKV);
  WGEMM(256, QKV, 768, pk_two, t_bo, P4, out, nullptr,
        36864, 256, 1, 0, 0, 0);

  // ---- CLS frame spatial mean + broadcast (on out = x2) ----
  cls_sum_kernel<<<128, 256, 0, stream>>>(out, clsp);
  cls_bcast_kernel<<<32, 256, 0, stream>>>(out, clsp);

  // ---- FUSED MLP v4 (ln + w1 + gelu + w2 + resid), in place on out ----
  mlp_fused_kernel<<<1152, 256, 0, stream>>>(out, pk_w1, b1, pk_w2, b2,
                                             mln_g, mln_b);
  #undef WGEMM
}

// Round 11
// 482.323 us; speedup vs baseline: 2.0398x; 1.0219x over previous
//
#include <hip/hip_runtime.h>
#include <math.h>

#define TQ_  9

typedef unsigned int   u32;
typedef unsigned short ushort_t;
typedef short bf16x8 __attribute__((ext_vector_type(8)));
typedef float f32x4  __attribute__((ext_vector_type(4)));

__device__ __forceinline__ float bs2f(ushort_t s) {
  return __uint_as_float(((u32)s) << 16);
}
__device__ __forceinline__ ushort_t f2bs(float x) {   // round-to-nearest-even
  u32 u = __float_as_uint(x);
  u32 r = (u + 0x7FFFu + ((u >> 16) & 1u)) >> 16;
  return (ushort_t)r;
}

// fast gelu: 0.5x(1+erf(x/sqrt2)), erf via Abramowitz-Stegun 7.1.26
// (|abs err| < 1.5e-7, far below bf16 rounding). ~15 VALU ops vs erff's ~30+.
__device__ __forceinline__ float gelu_f(float x) {
  float z = x * 0.70710678118654752f;
  float a = fabsf(z);
  float t = __builtin_amdgcn_rcpf(1.f + 0.3275911f * a);
  float poly = t * (0.254829592f + t * (-0.284496736f +
               t * (1.421413741f + t * (-1.453152027f + t * 1.061405429f))));
  float erfv = 1.f - poly * __expf(-z * z);
  erfv = (z < 0.f) ? -erfv : erfv;
  return 0.5f * x * (1.f + erfv);
}

// ---------------------------------------------------------------------------
// Weight PACK: W f32 [K][N] -> MFMA-frag-linear bf16 (A-operand layout).
// Frag group G = (j*(K/32) + kk)*64 + q*16 + ln holds 8 bf16:
//   element e: out-col n = j*16+ln, k = kk*32 + q*8 + e.
// pm=1 (Q/K weights): out-columns permuted within each 32-col head so RoPE
// pairs (d, d+16) sit at positions c, c^8 of a 16-col chunk.
// ---------------------------------------------------------------------------
struct TPA { const float* s[10]; ushort_t* d[10]; int K[10]; int N[10]; int pm[10]; };

__global__ __launch_bounds__(256)
void pack_all_kernel(TPA p) {
  int z = blockIdx.z;
  int K = p.K[z], N = p.N[z];
  int bn = blockIdx.x << 5, bk = blockIdx.y << 5;
  if (bn >= N || bk >= K) return;
  const float* W = p.s[z];
  ushort_t* pk = p.d[z];
  int pm = p.pm[z];
  __shared__ float t[32][33];                 // [k_local][n_local]
  int tid = threadIdx.x;
  int tx = tid & 31, ty = tid >> 5;
  #pragma unroll
  for (int r = 0; r < 4; ++r)
    t[ty + (r << 3)][tx] = W[(long)(bk + ty + (r << 3)) * N + bn + tx];
  __syncthreads();
  if (tid < 128) {
    int jl = tid >> 6, q = (tid >> 4) & 3, ln = tid & 15;
    int j = (bn >> 4) + jl, kk = bk >> 5;
    int colsrc = pm ? ((ln & 7) + (jl << 3) + ((ln & 8) << 1))
                    : ((jl << 4) + ln);
    long G = (((long)j * (K >> 5) + kk) << 6) + (q << 4) + ln;
    bf16x8 ov;
    #pragma unroll
    for (int e = 0; e < 8; ++e)
      ov[e] = (short)f2bs(t[(q << 3) + e][colsrc]);
    *(bf16x8*)(pk + (G << 3)) = ov;
  }
}

// concat 3 biases x 2 stages into f32 [2][768]; Q/K parts permuted to match
struct BC6 { const float* b[6]; };
__global__ __launch_bounds__(768)
void bias_concat_kernel(BC6 p, float* __restrict__ dst) {
  int z = blockIdx.x, n = threadIdx.x;
  int w = n >> 8, q = n & 255;
  int psrc = q;
  if (w < 2)
    psrc = (q & 0xE0) | (q & 7) | (((q >> 4) & 1) << 3) | (((q >> 3) & 1) << 4);
  dst[z * 768 + n] = p.b[z * 3 + w][psrc];
}

// ---------------------------------------------------------------------------
// LayerNorm materialize: one wave per row (4 rows/block), float4 loads.
// ---------------------------------------------------------------------------
__global__ __launch_bounds__(256)
void ln_norm_kernel(const float* __restrict__ src, int spatial,
                    const float* __restrict__ g, const float* __restrict__ b,
                    ushort_t* __restrict__ dst) {
  int row = blockIdx.x * 4 + (threadIdx.x >> 6);
  int lane = threadIdx.x & 63;
  long srow = row;
  if (spatial) {
    int bq = row >> 13, r = row & 8191;
    srow = ((long)(bq * TQ_ + (r >> 10)) << 10) + (r & 1023);
  }
  float4 v = ((const float4*)(src + srow * 256))[lane];
  float s  = v.x + v.y + v.z + v.w;
  float s2 = v.x * v.x + v.y * v.y + v.z * v.z + v.w * v.w;
  #pragma unroll
  for (int m = 32; m; m >>= 1) {
    s  += __shfl_xor(s,  m, 64);
    s2 += __shfl_xor(s2, m, 64);
  }
  float mean = s * (1.f / 256.f);
  float rstd = rsqrtf(s2 * (1.f / 256.f) - mean * mean + 1e-5f);
  float4 gv = ((const float4*)g)[lane];
  float4 bv = ((const float4*)b)[lane];
  ushort_t o[4];
  o[0] = f2bs((v.x - mean) * rstd * gv.x + bv.x);
  o[1] = f2bs((v.y - mean) * rstd * gv.y + bv.y);
  o[2] = f2bs((v.z - mean) * rstd * gv.z + bv.z);
  o[3] = f2bs((v.w - mean) * rstd * gv.w + bv.w);
  u32 lo = (u32)o[0] | ((u32)o[1] << 16);
  u32 hi = (u32)o[2] | ((u32)o[3] << 16);
  uint2 pk; pk.x = lo; pk.y = hi;
  *(uint2*)(dst + (long)row * 256 + lane * 4) = pk;
}

// ---------------------------------------------------------------------------
// Barrier-free register-streaming GEMM (no LDS), swapped operand order:
//   D = W_frag (A-op, n-rows) x X_frag (B-op, m-cols) -> lane-contiguous cols.
// (unchanged from round 5 — verified, handles the 4 attn-stage GEMMs)
// ---------------------------------------------------------------------------
template<int K>
__global__ __launch_bounds__(256, 4)
void wgemm_kernel(const ushort_t* __restrict__ A, int lda,
                  const ushort_t* __restrict__ packW,
                  const float* __restrict__ bias, const float* __restrict__ resid,
                  float* __restrict__ Cf, ushort_t* __restrict__ Cb,
                  int N, int NBq, int resid_mode, int out_mode, int act, int rope) {
  constexpr int K32 = K / 32;
  constexpr int AD = (K32 >= 4) ? 4 : K32;    // X prefetch depth (reg ring)
  constexpr int BD = 2;                       // W prefetch depth

  int tid = threadIdx.x;
  int wv = tid >> 6, lane = tid & 63;
  int ln = lane & 15, q4 = lane >> 4;

  // XCD-grouping decode
  int gid = blockIdx.x;
  int g = gid >> 5, r = gid & 31;
  int nq = (r >> 3) + ((g % NBq) << 2);
  int mb = ((g / NBq) << 3) + (r & 7);
  int m0 = mb << 7, n0 = nq << 6;

  const ushort_t* Ap = A + (long)(m0 + (wv << 5) + ln) * lda + (q4 << 3);
  long a16 = (long)lda << 4;                  // +16 rows
  const ushort_t* Bp = packW + (((long)(nq << 2) * K32) << 9) + (lane << 3);

  bf16x8 xr[AD][2];                           // X fragments (B-operand)
  bf16x8 wr[BD][4];                           // W fragments (A-operand)
  #pragma unroll
  for (int d = 0; d < BD; ++d)
    #pragma unroll
    for (int j = 0; j < 4; ++j)
      wr[d][j] = *(const bf16x8*)(Bp + (((long)j * K32 + d) << 9));
  #pragma unroll
  for (int d = 0; d < AD; ++d) {
    xr[d][0] = *(const bf16x8*)(Ap + d * 32);
    xr[d][1] = *(const bf16x8*)(Ap + a16 + d * 32);
  }

  f32x4 acc[2][4];
  #pragma unroll
  for (int i = 0; i < 2; ++i)
    #pragma unroll
    for (int j = 0; j < 4; ++j) acc[i][j] = 0.f;

  #pragma unroll
  for (int kk = 0; kk < K32; ++kk) {          // fully unrolled: static indices
    #pragma unroll
    for (int i = 0; i < 2; ++i)
      #pragma unroll
      for (int j = 0; j < 4; ++j)
        acc[i][j] = __builtin_amdgcn_mfma_f32_16x16x32_bf16(
            wr[kk % BD][j], xr[kk % AD][i], acc[i][j], 0, 0, 0);
    if (kk + AD < K32) {
      xr[kk % AD][0] = *(const bf16x8*)(Ap + (kk + AD) * 32);
      xr[kk % AD][1] = *(const bf16x8*)(Ap + a16 + (kk + AD) * 32);
    }
    if (kk + BD < K32) {
      #pragma unroll
      for (int j = 0; j < 4; ++j)
        wr[kk % BD][j] = *(const bf16x8*)(Bp + (((long)j * K32 + kk + BD) << 9));
    }
    __builtin_amdgcn_sched_barrier(0);        // pin prefetch distance
  }

  // ---- epilogue (all lane-contiguous: float4 / uint2) ----
  float4 bj[4];
  #pragma unroll
  for (int j = 0; j < 4; ++j)
    bj[j] = *(const float4*)(bias + n0 + (j << 4) + (q4 << 2));

  float cs_c[2][4], cs_s[2][4];
  if (rope) {
    int t = (m0 >> 10) % TQ_;
    #pragma unroll
    for (int p = 0; p < 2; ++p)
      #pragma unroll
      for (int r2 = 0; r2 < 4; ++r2) {
        float d = (float)(((q4 & 1) << 2) + r2 + (p << 3));
        float ang = (float)t * exp2f(d * -0.8304820237218406f);
        cs_c[p][r2] = cosf(ang);
        float s = sinf(ang);
        cs_s[p][r2] = (q4 & 2) ? s : -s;      // x1 lanes: -s, x2 lanes: +s
      }
  }

  #pragma unroll
  for (int i = 0; i < 2; ++i) {
    int m = m0 + (wv << 5) + (i << 4) + ln;   // per-lane output row
    long orow = m;
    if (out_mode == 1 || resid_mode == 2) {
      int bq = m >> 13, rr = m & 8191;
      orow = ((long)(bq * TQ_ + (rr >> 10)) << 10) + (rr & 1023);
    }
    #pragma unroll
    for (int j = 0; j < 4; ++j) {
      int n = n0 + (j << 4) + (q4 << 2);      // 4 consecutive cols per lane
      float v[4];
      #pragma unroll
      for (int r2 = 0; r2 < 4; ++r2) v[r2] = acc[i][j][r2] + bj[j][r2];
      if (rope && ((nq << 2) + j) < 32) {     // Q,K region (first 512 cols)
        #pragma unroll
        for (int r2 = 0; r2 < 4; ++r2) {
          float other = __shfl_xor(v[r2], 32, 64);
          v[r2] = v[r2] * cs_c[j & 1][r2] + other * cs_s[j & 1][r2];
        }
      }
      if (act) {
        #pragma unroll
        for (int r2 = 0; r2 < 4; ++r2) v[r2] = gelu_f(v[r2]);
      }
      if (resid_mode == 1) {
        float4 rv = *(const float4*)(resid + (long)m * 256 + n);
        v[0] += rv.x; v[1] += rv.y; v[2] += rv.z; v[3] += rv.w;
      } else if (resid_mode == 2) {
        float4 rv = *(const float4*)(resid + orow * 256 + n);
        v[0] += rv.x; v[1] += rv.y; v[2] += rv.z; v[3] += rv.w;
      }
      if (out_mode == 2) {
        uint2 pk;
        pk.x = (u32)f2bs(v[0]) | ((u32)f2bs(v[1]) << 16);
        pk.y = (u32)f2bs(v[2]) | ((u32)f2bs(v[3]) << 16);
        *(uint2*)(Cb + (long)m * N + n) = pk;
      } else {
        float4 o4; o4.x = v[0]; o4.y = v[1]; o4.z = v[2]; o4.w = v[3];
        if (out_mode == 1) *(float4*)(Cf + orow * 256 + n) = o4;
        else               *(float4*)(Cf + (long)m * N + n) = o4;
      }
    }
  }
}

// ---------------------------------------------------------------------------
// FUSED MLP v5: out = x + (gelu(LN(x) @ W1 + b1) @ W2 + b2), in place.
// ROUND-10 LESSON: occupancy 2.3x'd but dur only -11% -> per-wave serial
// chain (~2560cy MFMA + ~4000cy VALU + 9 barriers) still binds. v5 keeps
// the 32-row/1152-block tile and 32 KB LDS but uses 512 THREADS (8 waves):
// per-wave work halves (w1: one 32-col hid chunk/quarter = 32 MFMA; w2:
// 32 out cols, acc[2][2] = 16 VGPR) and waves/CU doubles (4 blocks x 8 =
// 32-wave cap). Same traffic, same swizzles, exact gelu (one variable).
// Phases: LN (4 rows/wave, 16 lanes/row) -> sync -> 4x { w1+gelu->HLDS ->
// sync -> w2 partial acc -> sync } -> epilogue.
// ---------------------------------------------------------------------------
__device__ __forceinline__ int tl_off(int row, int col) {   // 256-col bf16 tile
  return (row << 8) + (((((col >> 3) + row) & 31)) << 3) + (col & 7);
}

__global__ __launch_bounds__(512, 6)
void mlp_fused_kernel(float* xio,                       // in/out (same buffer)
                      const ushort_t* __restrict__ W1p, // packed [1024][256]
                      const float* __restrict__ b1,
                      const ushort_t* __restrict__ W2p, // packed [256][1024]
                      const float* __restrict__ b2,
                      const float* __restrict__ g,
                      const float* __restrict__ be) {
  __shared__ ushort_t XL[8192];     // 16 KB: 32x256 normalized X (swizzled)
  __shared__ ushort_t HLDS[8192];   // 16 KB: 32x256 hid quarter (swizzled)
  int tid = threadIdx.x;
  int wv = tid >> 6, lane = tid & 63;   // wv in [0,8)
  int ln = lane & 15, q4 = lane >> 4;
  int m0 = blockIdx.x << 5;                   // 32 rows

  // ---- LN: wave wv rows wv*4..+3; 16 lanes/row (shfl_xor 1,2,4,8) ----
  {
    int lrow = (wv << 2) + (lane >> 4);       // local row 0..31
    int p = lane & 15;
    const float* xr = xio + (long)(m0 + lrow) * 256 + (p << 2);
    float s = 0.f, s2 = 0.f;
    float4 vbuf[4];
    #pragma unroll
    for (int k = 0; k < 4; ++k) {
      float4 a = *(const float4*)(xr + (k << 6));
      vbuf[k] = a;
      s  += a.x + a.y + a.z + a.w;
      s2 += a.x*a.x + a.y*a.y + a.z*a.z + a.w*a.w;
    }
    s  += __shfl_xor(s,  1, 64);  s  += __shfl_xor(s,  2, 64);
    s  += __shfl_xor(s,  4, 64);  s  += __shfl_xor(s,  8, 64);
    s2 += __shfl_xor(s2, 1, 64);  s2 += __shfl_xor(s2, 2, 64);
    s2 += __shfl_xor(s2, 4, 64);  s2 += __shfl_xor(s2, 8, 64);
    float mean = s * (1.f / 256.f);
    float rstd = rsqrtf(s2 * (1.f / 256.f) - mean * mean + 1e-5f);
    #pragma unroll
    for (int k = 0; k < 4; ++k) {
      int col = (p << 2) + (k << 6);
      float4 gv = *(const float4*)(g + col);
      float4 bv = *(const float4*)(be + col);
      float4 a = vbuf[k];
      u32 lo = (u32)f2bs((a.x - mean) * rstd * gv.x + bv.x)
             | ((u32)f2bs((a.y - mean) * rstd * gv.y + bv.y) << 16);
      u32 hi = (u32)f2bs((a.z - mean) * rstd * gv.z + bv.z)
             | ((u32)f2bs((a.w - mean) * rstd * gv.w + bv.w) << 16);
      uint2 pk; pk.x = lo; pk.y = hi;
      *(uint2*)&XL[tl_off(lrow, col)] = pk;
    }
  }
  __syncthreads();

  f32x4 acc[2][2];                            // out acc: 2 i x 2 jl (16 VGPR)
  #pragma unroll
  for (int i = 0; i < 2; ++i)
    #pragma unroll
    for (int jl = 0; jl < 2; ++jl) acc[i][jl] = 0.f;

  #pragma unroll 1
  for (int q = 0; q < 4; ++q) {               // hid quarters of 256 cols
    // ---- w1: wave wv -> global 32-col hid chunk c32 = q*8+wv ----
    {
      int c32 = (q << 3) + wv;
      f32x4 h[2][2];
      #pragma unroll
      for (int i = 0; i < 2; ++i)
        #pragma unroll
        for (int jj = 0; jj < 2; ++jj) h[i][jj] = 0.f;

      bf16x8 wf[2][2];
      #pragma unroll
      for (int jj = 0; jj < 2; ++jj)
        wf[0][jj] = *(const bf16x8*)(W1p +
            (((long)((c32 << 1) + jj) * 8) << 9) + (lane << 3));
      #pragma unroll
      for (int ks = 0; ks < 8; ++ks) {
        if (ks + 1 < 8) {                     // prefetch next (no WAR: other buf)
          #pragma unroll
          for (int jj = 0; jj < 2; ++jj)
            wf[(ks + 1) & 1][jj] = *(const bf16x8*)(W1p +
                (((long)((c32 << 1) + jj) * 8 + ks + 1) << 9) + (lane << 3));
        }
        int col = (q4 << 3) + (ks << 5);
        bf16x8 xf0 = *(const bf16x8*)&XL[tl_off(ln, col)];
        bf16x8 xf1 = *(const bf16x8*)&XL[tl_off(16 + ln, col)];
        #pragma unroll
        for (int jj = 0; jj < 2; ++jj) {
          h[0][jj] = __builtin_amdgcn_mfma_f32_16x16x32_bf16(
              wf[ks & 1][jj], xf0, h[0][jj], 0, 0, 0);
          h[1][jj] = __builtin_amdgcn_mfma_f32_16x16x32_bf16(
              wf[ks & 1][jj], xf1, h[1][jj], 0, 0, 0);
        }
        __builtin_amdgcn_sched_barrier(0);
      }
      // +b1, gelu, pack -> HLDS (local col = wv*32 + jj*16 + q4*4)
      #pragma unroll
      for (int jj = 0; jj < 2; ++jj) {
        float4 b1v = *(const float4*)(b1 + (c32 << 5) + (jj << 4) + (q4 << 2));
        #pragma unroll
        for (int i = 0; i < 2; ++i) {
          float v[4];
          v[0] = gelu_f(h[i][jj][0] + b1v.x);
          v[1] = gelu_f(h[i][jj][1] + b1v.y);
          v[2] = gelu_f(h[i][jj][2] + b1v.z);
          v[3] = gelu_f(h[i][jj][3] + b1v.w);
          uint2 pk;
          pk.x = (u32)f2bs(v[0]) | ((u32)f2bs(v[1]) << 16);
          pk.y = (u32)f2bs(v[2]) | ((u32)f2bs(v[3]) << 16);
          *(uint2*)&HLDS[tl_off((i << 4) + ln, (wv << 5) + (jj << 4) + (q4 << 2))] = pk;
        }
      }
    }
    __syncthreads();

    // ---- w2 partial: wave wv -> out cols (wv*2+jl)*16..; k = quarter ----
    {
      bf16x8 wf2[2][2];
      #pragma unroll
      for (int jl = 0; jl < 2; ++jl)
        wf2[0][jl] = *(const bf16x8*)(W2p +
            (((long)((wv << 1) + jl) * 32 + (q << 3)) << 9) + (lane << 3));
      #pragma unroll
      for (int kc = 0; kc < 8; ++kc) {
        if (kc + 1 < 8) {
          #pragma unroll
          for (int jl = 0; jl < 2; ++jl)
            wf2[(kc + 1) & 1][jl] = *(const bf16x8*)(W2p +
                (((long)((wv << 1) + jl) * 32 + (q << 3) + kc + 1) << 9) + (lane << 3));
        }
        int col = (kc << 5) + (q4 << 3);
        bf16x8 hb0 = *(const bf16x8*)&HLDS[tl_off(ln, col)];
        bf16x8 hb1 = *(const bf16x8*)&HLDS[tl_off(16 + ln, col)];
        #pragma unroll
        for (int jl = 0; jl < 2; ++jl) {
          acc[0][jl] = __builtin_amdgcn_mfma_f32_16x16x32_bf16(
              wf2[kc & 1][jl], hb0, acc[0][jl], 0, 0, 0);
          acc[1][jl] = __builtin_amdgcn_mfma_f32_16x16x32_bf16(
              wf2[kc & 1][jl], hb1, acc[1][jl], 0, 0, 0);
        }
        __builtin_amdgcn_sched_barrier(0);
      }
    }
    __syncthreads();                          // before next quarter overwrites HLDS
  }

  // ---- epilogue: +b2 +resid(x), float4 stores, in place ----
  #pragma unroll
  for (int i = 0; i < 2; ++i) {
    long ro = (long)(m0 + (i << 4) + ln) * 256;
    #pragma unroll
    for (int jl = 0; jl < 2; ++jl) {
      int n = ((wv << 1) + jl) * 16 + (q4 << 2);
      float4 rv = *(const float4*)(xio + ro + n);
      float4 bv = *(const float4*)(b2 + n);
      float4 o;
      o.x = acc[i][jl][0] + bv.x + rv.x;
      o.y = acc[i][jl][1] + bv.y + rv.y;
      o.z = acc[i][jl][2] + bv.z + rv.z;
      o.w = acc[i][jl][3] + bv.w + rv.w;
      *(float4*)(xio + ro + n) = o;
    }
  }
}

// ---------------------------------------------------------------------------
// Spatial 3x3 windowed attention on packed QKV [m][768] bf16.
// ---------------------------------------------------------------------------
__global__ __launch_bounds__(256)
void spatial_attn_kernel(ushort_t* __restrict__ qkv) {
  int gid = blockIdx.x * 256 + threadIdx.x;   // 262144
  int head = gid & 7, pixel = gid >> 3;
  int pix = pixel & 1023, bt = pixel >> 10;
  int y = pix >> 5, x = pix & 31;
  long rb = (long)bt << 10;
  const float scale = 0.17677669529663687f;   // 1/sqrt(32)

  float qf[32];
  long qoff = (long)pixel * 768 + head * 32;
  #pragma unroll
  for (int i = 0; i < 4; ++i) {
    bf16x8 t = *(const bf16x8*)(qkv + qoff + i * 8);
    #pragma unroll
    for (int e = 0; e < 8; ++e) qf[i * 8 + e] = bs2f((ushort_t)t[e]);
  }

  float s[9];
  bool val[9];
  #pragma unroll
  for (int n = 0; n < 9; ++n) {
    int yy = y + n / 3 - 1, xx = x + n % 3 - 1;
    bool ok = ((unsigned)yy < 32u) & ((unsigned)xx < 32u);
    val[n] = ok;
    float d = 0.f;
    if (ok) {
      long ko = (rb + (yy << 5) + xx) * 768 + 256 + head * 32;
      #pragma unroll
      for (int i = 0; i < 4; ++i) {
        bf16x8 t = *(const bf16x8*)(qkv + ko + i * 8);
        #pragma unroll
        for (int e = 0; e < 8; ++e) d += qf[i * 8 + e] * bs2f((ushort_t)t[e]);
      }
    }
    s[n] = d * scale;
  }
  float mx = -1e30f;
  #pragma unroll
  for (int n = 0; n < 9; ++n) if (val[n]) mx = fmaxf(mx, s[n]);
  float sum = 0.f;
  #pragma unroll
  for (int n = 0; n < 9; ++n) { s[n] = val[n] ? __expf(s[n] - mx) : 0.f; sum += s[n]; }
  float inv = 1.f / sum;

  float o[32];
  #pragma unroll
  for (int i = 0; i < 32; ++i) o[i] = 0.f;
  #pragma unroll
  for (int n = 0; n < 9; ++n) {
    if (val[n]) {
      int yy = y + n / 3 - 1, xx = x + n % 3 - 1;
      long vo = (rb + (yy << 5) + xx) * 768 + 512 + head * 32;
      #pragma unroll
      for (int i = 0; i < 4; ++i) {
        bf16x8 t = *(const bf16x8*)(qkv + vo + i * 8);
        #pragma unroll
        for (int e = 0; e < 8; ++e) o[i * 8 + e] += s[n] * bs2f((ushort_t)t[e]);
      }
    }
  }
  #pragma unroll
  for (int i = 0; i < 4; ++i) {
    bf16x8 t;
    #pragma unroll
    for (int e = 0; e < 8; ++e) t[e] = (short)f2bs(o[i * 8 + e] * inv);
    *(bf16x8*)(qkv + qoff + i * 8) = t;
  }
}

// ---------------------------------------------------------------------------
// Temporal attention (full 9x9; mask all-False). o over q in-place.
// ---------------------------------------------------------------------------
__global__ __launch_bounds__(256)
void temporal_attn_kernel(ushort_t* __restrict__ qkv) {
  int tid = threadIdx.x;
  int head = tid & 7, hwi = tid >> 3;
  int bi = blockIdx.x;                          // 1152 = 9 * 4 * 32
  int tq = bi >> 7;
  int rest = bi & 127;
  int b = rest >> 5, hwg = rest & 31;
  int hw = (hwg << 5) + hwi;
  long base = (long)(b * TQ_) * 1024 + hw;
  const float scale = 0.17677669529663687f;

  float qf[32];
  long qoff = (base + (long)tq * 1024) * 768 + head * 32;
  #pragma unroll
  for (int i = 0; i < 4; ++i) {
    bf16x8 t = *(const bf16x8*)(qkv + qoff + i * 8);
    #pragma unroll
    for (int e = 0; e < 8; ++e) qf[i * 8 + e] = bs2f((ushort_t)t[e]);
  }
  float s[9];
  #pragma unroll
  for (int tk = 0; tk < 9; ++tk) {
    long ko = (base + (long)tk * 1024) * 768 + 256 + head * 32;
    float d = 0.f;
    #pragma unroll
    for (int i = 0; i < 4; ++i) {
      bf16x8 t = *(const bf16x8*)(qkv + ko + i * 8);
      #pragma unroll
      for (int e = 0; e < 8; ++e) d += qf[i * 8 + e] * bs2f((ushort_t)t[e]);
    }
    s[tk] = d * scale;
  }
  float mx = s[0];
  #pragma unroll
  for (int tk = 1; tk < 9; ++tk) mx = fmaxf(mx, s[tk]);
  float sum = 0.f;
  #pragma unroll
  for (int tk = 0; tk < 9; ++tk) { s[tk] = __expf(s[tk] - mx); sum += s[tk]; }
  float inv = 1.f / sum;

  float o[32];
  #pragma unroll
  for (int i = 0; i < 32; ++i) o[i] = 0.f;
  #pragma unroll
  for (int tk = 0; tk < 9; ++tk) {
    long vo = (base + (long)tk * 1024) * 768 + 512 + head * 32;
    #pragma unroll
    for (int i = 0; i < 4; ++i) {
      bf16x8 t = *(const bf16x8*)(qkv + vo + i * 8);
      #pragma unroll
      for (int e = 0; e < 8; ++e) o[i * 8 + e] += s[tk] * bs2f((ushort_t)t[e]);
    }
  }
  #pragma unroll
  for (int i = 0; i < 4; ++i) {
    bf16x8 t;
    #pragma unroll
    for (int e = 0; e < 8; ++e) t[e] = (short)f2bs(o[i * 8 + e] * inv);
    *(bf16x8*)(qkv + qoff + i * 8) = t;
  }
}

// copy query frame 8 into x (f32); identical linear indices in both buffers
__global__ __launch_bounds__(256)
void copy_frame8_kernel(const float* __restrict__ qy, float* __restrict__ x) {
  long i = (long)blockIdx.x * 256 + threadIdx.x;
  int b = (int)(i >> 18);
  long rem = i & ((1L << 18) - 1);
  long gi = ((long)(b * TQ_ + 8) << 18) + rem;
  x[gi] = qy[gi];
}

// CLS frame mean over spatial: partial sums then broadcast (on f32 x)
__global__ __launch_bounds__(256)
void cls_sum_kernel(const float* __restrict__ x, float* __restrict__ partial) {
  int b = blockIdx.x >> 5, ch = blockIdx.x & 31;
  int d = threadIdx.x;
  long base = ((long)(b * TQ_) * 1024 + ch * 32) * 256 + d;
  float s = 0.f;
  for (int r = 0; r < 32; ++r) s += x[base + (long)r * 256];
  partial[(long)blockIdx.x * 256 + d] = s;
}

__global__ __launch_bounds__(256)
void cls_bcast_kernel(float* __restrict__ x, const float* __restrict__ partial) {
  int b = blockIdx.x >> 3, seg = blockIdx.x & 7;
  int d = threadIdx.x;
  float s = 0.f;
  for (int j = 0; j < 32; ++j) s += partial[(long)(b * 32 + j) * 256 + d];
  s *= (1.f / 1024.f);
  long base = ((long)(b * TQ_) * 1024 + seg * 128) * 256 + d;
  for (int r = 0; r < 128; ++r) x[base + (long)r * 256] = s;
}

// ---------------------------------------------------------------------------
extern "C" void kernel_launch(void* const* d_in, const int* in_sizes, int n_in,
                              void* d_out, int out_size, void* d_ws, size_t ws_size,
                              hipStream_t stream) {
  (void)in_sizes; (void)n_in; (void)out_size; (void)ws_size;
  const float* query = (const float*)d_in[0];
  const float* sln_g = (const float*)d_in[3];
  const float* sln_b = (const float*)d_in[4];
  const float* s_wq  = (const float*)d_in[5];
  const float* s_bq  = (const float*)d_in[6];
  const float* s_wk  = (const float*)d_in[7];
  const float* s_bk  = (const float*)d_in[8];
  const float* s_wv  = (const float*)d_in[9];
  const float* s_bv  = (const float*)d_in[10];
  const float* s_wo  = (const float*)d_in[11];
  const float* s_bo  = (const float*)d_in[12];
  const float* tln_g = (const float*)d_in[13];
  const float* tln_b = (const float*)d_in[14];
  const float* t_wq  = (const float*)d_in[15];
  const float* t_bq  = (const float*)d_in[16];
  const float* t_wk  = (const float*)d_in[17];
  const float* t_bk  = (const float*)d_in[18];
  const float* t_wv  = (const float*)d_in[19];
  const float* t_bv  = (const float*)d_in[20];
  const float* t_wo  = (const float*)d_in[21];
  const float* t_bo  = (const float*)d_in[22];
  const float* mln_g = (const float*)d_in[23];
  const float* mln_b = (const float*)d_in[24];
  const float* w1    = (const float*)d_in[25];
  const float* b1    = (const float*)d_in[26];
  const float* w2    = (const float*)d_in[27];
  const float* b2    = (const float*)d_in[28];
  float* out = (float*)d_out;

  // ---- workspace ----
  const long RB = 36864L * 256;
  ushort_t* XA  = (ushort_t*)d_ws;          // RB bf16
  ushort_t* QKV = XA + RB;                  // 3*RB bf16, rows of 768
  float*    P4  = (float*)(QKV + 3 * RB);   // RB f32
  ushort_t* wt  = (ushort_t*)(P4 + RB);     // 2 MB packed weights
  float* bias2  = (float*)(wt + 1048576);   // 2x768 f32
  float* clsp   = bias2 + 1536;             // 128*256 f32

  ushort_t* pk_sqkv = wt;                   // packed [768][256]
  ushort_t* pk_tqkv = wt + 196608;          // packed [768][256]
  ushort_t* pk_swo  = wt + 393216;          // packed [256][256]
  ushort_t* pk_two  = wt + 458752;          // packed [256][256]
  ushort_t* pk_w1   = wt + 524288;          // packed [1024][256]
  ushort_t* pk_w2   = wt + 786432;          // packed [256][1024]

  // ---- weight / bias prep (one pack dispatch) ----
  TPA tp;
  tp.s[0] = s_wq; tp.d[0] = pk_sqkv;          tp.K[0] = 256;  tp.N[0] = 256;  tp.pm[0] = 1;
  tp.s[1] = s_wk; tp.d[1] = pk_sqkv + 65536;  tp.K[1] = 256;  tp.N[1] = 256;  tp.pm[1] = 1;
  tp.s[2] = s_wv; tp.d[2] = pk_sqkv + 131072; tp.K[2] = 256;  tp.N[2] = 256;  tp.pm[2] = 0;
  tp.s[3] = t_wq; tp.d[3] = pk_tqkv;          tp.K[3] = 256;  tp.N[3] = 256;  tp.pm[3] = 1;
  tp.s[4] = t_wk; tp.d[4] = pk_tqkv + 65536;  tp.K[4] = 256;  tp.N[4] = 256;  tp.pm[4] = 1;
  tp.s[5] = t_wv; tp.d[5] = pk_tqkv + 131072; tp.K[5] = 256;  tp.N[5] = 256;  tp.pm[5] = 0;
  tp.s[6] = s_wo; tp.d[6] = pk_swo;           tp.K[6] = 256;  tp.N[6] = 256;  tp.pm[6] = 0;
  tp.s[7] = t_wo; tp.d[7] = pk_two;           tp.K[7] = 256;  tp.N[7] = 256;  tp.pm[7] = 0;
  tp.s[8] = w1;   tp.d[8] = pk_w1;            tp.K[8] = 256;  tp.N[8] = 1024; tp.pm[8] = 0;
  tp.s[9] = w2;   tp.d[9] = pk_w2;            tp.K[9] = 1024; tp.N[9] = 256;  tp.pm[9] = 0;
  pack_all_kernel<<<dim3(32, 32, 10), 256, 0, stream>>>(tp);
  BC6 bc;
  bc.b[0] = s_bq; bc.b[1] = s_bk; bc.b[2] = s_bv;
  bc.b[3] = t_bq; bc.b[4] = t_bk; bc.b[5] = t_bv;
  bias_concat_kernel<<<2, 768, 0, stream>>>(bc, bias2);

  // grid = (M/128)*(N/64) blocks, XCD-group-swizzled inside; NBq = N/256
  #define WGEMM(KV, Ap, ldav, Wp, bi, rs, CF, CB, M, N, rm, om, ac, rp)     \
    wgemm_kernel<KV><<<dim3(((M) / 128) * ((N) / 64)), 256, 0, stream>>>(   \
        Ap, ldav, Wp, bi, rs, CF, CB, N, (N) / 256, rm, om, ac, rp)

  // ---- spatial windowed attention (frames 0..7), M=32768 ----
  ln_norm_kernel<<<8192, 256, 0, stream>>>(query, 1, sln_g, sln_b, XA);
  WGEMM(256, XA, 256, pk_sqkv, bias2, nullptr, nullptr, QKV,
        32768, 768, 0, 2, 0, 0);
  spatial_attn_kernel<<<1024, 256, 0, stream>>>(QKV);
  WGEMM(256, QKV, 768, pk_swo, s_bo, query, P4, nullptr,
        32768, 256, 2, 1, 0, 0);
  copy_frame8_kernel<<<4096, 256, 0, stream>>>(query, P4);

  // ---- temporal RoPE attention, M=36864 ----
  ln_norm_kernel<<<9216, 256, 0, stream>>>(P4, 0, tln_g, tln_b, XA);
  WGEMM(256, XA, 256, pk_tqkv, bias2 + 768, nullptr, nullptr, QKV,
        36864, 768, 0, 2, 0, 1);
  temporal_attn_kernel<<<1152, 256, 0, stream>>>(QKV);
  WGEMM(256, QKV, 768, pk_two, t_bo, P4, out, nullptr,
        36864, 256, 1, 0, 0, 0);

  // ---- CLS frame spatial mean + broadcast (on out = x2) ----
  cls_sum_kernel<<<128, 256, 0, stream>>>(out, clsp);
  cls_bcast_kernel<<<32, 256, 0, stream>>>(out, clsp);

  // ---- FUSED MLP v5 (ln + w1 + gelu + w2 + resid), in place on out ----
  mlp_fused_kernel<<<1152, 512, 0, stream>>>(out, pk_w1, b1, pk_w2, b2,
                                             mln_g, mln_b);
  #undef WGEMM
}